// Round 1
// baseline (846.226 us; speedup 1.0000x reference)
//
#include <hip/hip_runtime.h>
#include <math.h>

#define NTOPK 100
#define QC    6000
#define NC    20
#define EMBED 2700
#define IMGW  1024

// ---------------------------------------------------------------------------
// Kernel 1: per (stream, batch) top-100 of logits -> xyxy pixel boxes
// grid: 4 blocks (which*2+b), 256 threads
// ---------------------------------------------------------------------------
__global__ __launch_bounds__(256) void topk_boxes_kernel(
    const float* __restrict__ g_logits, const float* __restrict__ a_logits,
    const float* __restrict__ g_boxes,  const float* __restrict__ a_boxes,
    float* __restrict__ boxes_px /* [2][2][100][4] */) {
  const int which = blockIdx.x >> 1;
  const int b     = blockIdx.x & 1;
  const float* logits = (which ? a_logits : g_logits) + b * QC;
  const float* boxes  = (which ? a_boxes  : g_boxes)  + b * 300 * 4;
  float* outb = boxes_px + (size_t)(which * 2 + b) * NTOPK * 4;

  __shared__ float vals[QC];
  __shared__ float rv[4];
  __shared__ int   ri[4];
  const int tid = threadIdx.x;
  for (int j = tid; j < QC; j += 256) vals[j] = logits[j];
  __syncthreads();

  for (int it = 0; it < NTOPK; ++it) {
    float bv = -1e30f; int bi = 0x7fffffff;
    for (int j = tid; j < QC; j += 256) {
      float v = vals[j];
      if (v > bv) { bv = v; bi = j; }   // strict > keeps lowest index
    }
#pragma unroll
    for (int off = 32; off; off >>= 1) {
      float ov = __shfl_down(bv, off, 64);
      int   oi = __shfl_down(bi, off, 64);
      if (ov > bv || (ov == bv && oi < bi)) { bv = ov; bi = oi; }
    }
    if ((tid & 63) == 0) { rv[tid >> 6] = bv; ri[tid >> 6] = bi; }
    __syncthreads();
    if (tid == 0) {
      float v0 = rv[0]; int i0 = ri[0];
      for (int wq = 1; wq < 4; ++wq)
        if (rv[wq] > v0 || (rv[wq] == v0 && ri[wq] < i0)) { v0 = rv[wq]; i0 = ri[wq]; }
      vals[i0] = -1e30f;
      const int q = i0 / NC;
      const float cx = boxes[q*4+0], cy = boxes[q*4+1];
      const float w  = boxes[q*4+2], h  = boxes[q*4+3];
      // exact single-op arithmetic (no FMA contraction) to match numpy
      const float hw = __fmul_rn(0.5f, w), hh = __fmul_rn(0.5f, h);
      outb[it*4+0] = __fmul_rn(__fsub_rn(cx, hw), 1024.0f);
      outb[it*4+1] = __fmul_rn(__fsub_rn(cy, hh), 1024.0f);
      outb[it*4+2] = __fmul_rn(__fadd_rn(cx, hw), 1024.0f);
      outb[it*4+3] = __fmul_rn(__fadd_rn(cy, hh), 1024.0f);
    }
    __syncthreads();
  }
}

// ---------------------------------------------------------------------------
// Kernel 2: bilinear 30x30 ROI crops -> X rows (interleaved layout) + pos_enc
// grid: 400 blocks (which*200 + b*100 + t), 256 threads
// X row u = t*2 + b; pos_enc row = u % 100
// ---------------------------------------------------------------------------
__global__ __launch_bounds__(256) void roi_kernel(
    const float* __restrict__ g_samples, const float* __restrict__ a_samples,
    const float* __restrict__ boxes_px, const float* __restrict__ pos_enc,
    float* __restrict__ Xg, float* __restrict__ Xa) {
  const int which = blockIdx.x / 200;
  const int p     = blockIdx.x % 200;
  const int b = p / 100, t = p % 100;
  const float* img = (which ? a_samples : g_samples) + (size_t)b * 3 * IMGW * IMGW;
  const float* bx  = boxes_px + ((size_t)(which * 2 + b) * NTOPK + t) * 4;
  float* xrow = (which ? Xa : Xg) + (size_t)(t * 2 + b) * EMBED;
  const float* pe = pos_enc + (size_t)((t * 2 + b) % 100) * EMBED;

  __shared__ float s_wy[30], s_wx[30];
  __shared__ int   s_y0i[30], s_y1i[30], s_x0i[30], s_x1i[30];
  __shared__ float s_valid;

  const float x0 = rintf(bx[0]), y0 = rintf(bx[1]);
  const float x1 = rintf(bx[2]), y1 = rintf(bx[3]);
  const float w = __fsub_rn(x1, x0), h = __fsub_rn(y1, y0);
  const int tid = threadIdx.x;
  if (tid == 0) s_valid = (w > 0.0f && h > 0.0f) ? 1.0f : 0.0f;
  if (tid < 30) {
    const float g  = (float)tid + 0.5f;
    float sy = __fsub_rn(__fdiv_rn(__fmul_rn(g, h), 30.0f), 0.5f);
    const float hm1 = fmaxf(__fsub_rn(h, 1.0f), 0.0f);
    sy = fminf(fmaxf(sy, 0.0f), hm1);
    const float ay = __fadd_rn(y0, sy);
    const float yf = floorf(ay);
    s_wy[tid]  = __fsub_rn(ay, yf);
    s_y0i[tid] = (int)fminf(fmaxf(yf, 0.0f), 1023.0f);
    s_y1i[tid] = (int)fminf(fmaxf(yf + 1.0f, 0.0f), 1023.0f);
  } else if (tid >= 32 && tid < 62) {
    const int i = tid - 32;
    const float g = (float)i + 0.5f;
    float sx = __fsub_rn(__fdiv_rn(__fmul_rn(g, w), 30.0f), 0.5f);
    const float wm1 = fmaxf(__fsub_rn(w, 1.0f), 0.0f);
    sx = fminf(fmaxf(sx, 0.0f), wm1);
    const float ax = __fadd_rn(x0, sx);
    const float xf = floorf(ax);
    s_wx[i]  = __fsub_rn(ax, xf);
    s_x0i[i] = (int)fminf(fmaxf(xf, 0.0f), 1023.0f);
    s_x1i[i] = (int)fminf(fmaxf(xf + 1.0f, 0.0f), 1023.0f);
  }
  __syncthreads();
  const float valid = s_valid;
  for (int e = tid; e < EMBED; e += 256) {
    const int c = e / 900, pix = e % 900, py = pix / 30, px = pix % 30;
    const float* ic = img + (size_t)c * IMGW * IMGW;
    const int yi0 = s_y0i[py], yi1 = s_y1i[py], xi0 = s_x0i[px], xi1 = s_x1i[px];
    const float wy = s_wy[py], wx = s_wx[px];
    const float p00 = ic[yi0 * IMGW + xi0], p01 = ic[yi0 * IMGW + xi1];
    const float p10 = ic[yi1 * IMGW + xi0], p11 = ic[yi1 * IMGW + xi1];
    const float top = p00 * (1.0f - wx) + p01 * wx;
    const float bot = p10 * (1.0f - wx) + p11 * wx;
    const float val = top * (1.0f - wy) + bot * wy;
    xrow[e] = val * valid + pe[e];
  }
}

// ---------------------------------------------------------------------------
// Kernel 3a: zero the GEMM accumulators (ws is poisoned 0xAA)
// ---------------------------------------------------------------------------
__global__ void zero_kernel(float4* __restrict__ p, int n4) {
  const int i = blockIdx.x * blockDim.x + threadIdx.x;
  if (i < n4) p[i] = make_float4(0.f, 0.f, 0.f, 0.f);
}

// ---------------------------------------------------------------------------
// Kernel 3b: Y[200x2700] += X[200x2700] @ W^T, f32, tiled, K split x3
// grid (43, 4, 6): z = kc*2 + which ; block 256 (16x16), 4x4 microtile
// BM=BN=64, BK=36 (2700 = 36*75, 900 = 36*25)
// ---------------------------------------------------------------------------
#define GBK 36
#define LSTR 68   // LDS row stride (floats): breaks bank conflicts, keeps 16B align
__global__ __launch_bounds__(256) void gemm_kernel(
    const float* __restrict__ Xg, const float* __restrict__ Xa,
    const float* __restrict__ Wg, const float* __restrict__ Wa,
    float* __restrict__ Yg, float* __restrict__ Ya) {
  const int which = blockIdx.z & 1;
  const int kc    = blockIdx.z >> 1;          // 0..2, 900 K each
  const float* X = which ? Xa : Xg;
  const float* W = which ? Wa : Wg;
  float*       Y = which ? Ya : Yg;
  const int n0 = blockIdx.x * 64;
  const int m0 = blockIdx.y * 64;
  const int kbeg = kc * 900, kend = kbeg + 900;

  __shared__ alignas(16) float Xs[GBK][LSTR];
  __shared__ alignas(16) float Ws[GBK][LSTR];
  const int tid = threadIdx.x;
  const int tx = tid & 15, ty = tid >> 4;
  float acc[4][4] = {};

  for (int k0 = kbeg; k0 < kend; k0 += GBK) {
#pragma unroll
    for (int e = tid; e < 64 * GBK; e += 256) {
      const int r = e / GBK, k = e % GBK;
      const int m = m0 + r;
      Xs[k][r] = (m < 200) ? X[(size_t)m * EMBED + k0 + k] : 0.0f;
    }
#pragma unroll
    for (int e = tid; e < 64 * GBK; e += 256) {
      const int r = e / GBK, k = e % GBK;
      const int n = n0 + r;
      Ws[k][r] = (n < EMBED) ? W[(size_t)n * EMBED + k0 + k] : 0.0f;
    }
    __syncthreads();
#pragma unroll
    for (int k = 0; k < GBK; ++k) {
      const float4 a4 = *(const float4*)&Xs[k][ty * 4];
      const float4 b4 = *(const float4*)&Ws[k][tx * 4];
      const float av[4] = {a4.x, a4.y, a4.z, a4.w};
      const float bv[4] = {b4.x, b4.y, b4.z, b4.w};
#pragma unroll
      for (int i = 0; i < 4; ++i)
#pragma unroll
        for (int j = 0; j < 4; ++j) acc[i][j] += av[i] * bv[j];
    }
    __syncthreads();
  }
#pragma unroll
  for (int i = 0; i < 4; ++i) {
    const int m = m0 + ty * 4 + i;
    if (m >= 200) break;
#pragma unroll
    for (int j = 0; j < 4; ++j) {
      const int n = n0 + tx * 4 + j;
      if (n < EMBED) unsafeAtomicAdd(&Y[(size_t)m * EMBED + n], acc[i][j]);
    }
  }
}

// ---------------------------------------------------------------------------
// Kernel 4: sim[b,q,k] = Gt[b,q]·At[b,k] / sqrt(384); softmax over q; write out
// grid: 200 blocks (b2*100 + k), 256 threads (4 waves x 25 q each)
// ---------------------------------------------------------------------------
__global__ __launch_bounds__(256) void sim_softmax_kernel(
    const float* __restrict__ Gt, const float* __restrict__ At,
    float* __restrict__ out) {
  const int blk = blockIdx.x;
  const int b2 = blk / 100, k = blk % 100;
  const float* arow = At + (size_t)(b2 * 100 + k) * EMBED;
  __shared__ float s_a[EMBED];
  __shared__ float s_sim[100];
  __shared__ float s_m, s_d;
  const int tid = threadIdx.x;
  for (int j = tid; j < EMBED; j += 256) s_a[j] = arow[j];
  __syncthreads();
  const int wave = tid >> 6, lane = tid & 63;
  const float scale = sqrtf(384.0f);
  for (int q = wave; q < 100; q += 4) {
    const float* grow = Gt + (size_t)(b2 * 100 + q) * EMBED;
    float sum = 0.0f;
    for (int j = lane; j < EMBED; j += 64) sum += grow[j] * s_a[j];
#pragma unroll
    for (int off = 32; off; off >>= 1) sum += __shfl_down(sum, off, 64);
    if (lane == 0) s_sim[q] = sum / scale;
  }
  __syncthreads();
  if (tid < 64) {
    float m = -1e30f;
    for (int q = lane; q < 100; q += 64) m = fmaxf(m, s_sim[q]);
#pragma unroll
    for (int off = 32; off; off >>= 1) m = fmaxf(m, __shfl_down(m, off, 64));
    m = __shfl(m, 0, 64);
    float d = 0.0f;
    for (int q = lane; q < 100; q += 64) d += expf(s_sim[q] - m);
#pragma unroll
    for (int off = 32; off; off >>= 1) d += __shfl_down(d, off, 64);
    if (lane == 0) { s_m = m; s_d = d; }
  }
  __syncthreads();
  const float m = s_m, d = s_d;
  for (int q = tid; q < 100; q += 256)
    out[((size_t)b2 * 100 + q) * 100 + k] = expf(s_sim[q] - m) / d;
}

// ---------------------------------------------------------------------------
extern "C" void kernel_launch(void* const* d_in, const int* in_sizes, int n_in,
                              void* d_out, int out_size, void* d_ws, size_t ws_size,
                              hipStream_t stream) {
  const float* g_samples = (const float*)d_in[0];
  const float* a_samples = (const float*)d_in[1];
  const float* g_logits  = (const float*)d_in[2];
  const float* a_logits  = (const float*)d_in[3];
  const float* g_boxes   = (const float*)d_in[4];
  const float* a_boxes   = (const float*)d_in[5];
  const float* W_ground  = (const float*)d_in[6];
  const float* W_aerial  = (const float*)d_in[7];
  const float* pos_enc   = (const float*)d_in[8];
  float* out = (float*)d_out;
  float* ws  = (float*)d_ws;

  const size_t R = 540672;             // 200*2700 rounded up to 1024 multiple
  float* boxes_px = ws;                // 1600 floats
  float* Xg = ws + 2048;
  float* Xa = Xg + R;
  float* Gt = Xa + R;
  float* At = Gt + R;

  topk_boxes_kernel<<<4, 256, 0, stream>>>(g_logits, a_logits, g_boxes, a_boxes, boxes_px);
  roi_kernel<<<400, 256, 0, stream>>>(g_samples, a_samples, boxes_px, pos_enc, Xg, Xa);
  {
    const int n4 = (int)(2 * R / 4);   // zero Gt and At (contiguous)
    zero_kernel<<<(n4 + 255) / 256, 256, 0, stream>>>((float4*)Gt, n4);
  }
  gemm_kernel<<<dim3(43, 4, 6), 256, 0, stream>>>(Xg, Xa, W_ground, W_aerial, Gt, At);
  sim_softmax_kernel<<<200, 256, 0, stream>>>(Gt, At, out);
}

// Round 2
// 602.403 us; speedup vs baseline: 1.4047x; 1.4047x over previous
//
#include <hip/hip_runtime.h>
#include <math.h>

#define NTOPK 100
#define QC    6000
#define NC    20
#define EMBED 2700
#define IMGW  1024

// ---------------------------------------------------------------------------
// Kernel 1: per (stream, batch) top-100 of logits -> xyxy pixel boxes
// grid: 4 blocks (which*2+b), 256 threads
// ---------------------------------------------------------------------------
__global__ __launch_bounds__(256) void topk_boxes_kernel(
    const float* __restrict__ g_logits, const float* __restrict__ a_logits,
    const float* __restrict__ g_boxes,  const float* __restrict__ a_boxes,
    float* __restrict__ boxes_px /* [2][2][100][4] */) {
  const int which = blockIdx.x >> 1;
  const int b     = blockIdx.x & 1;
  const float* logits = (which ? a_logits : g_logits) + b * QC;
  const float* boxes  = (which ? a_boxes  : g_boxes)  + b * 300 * 4;
  float* outb = boxes_px + (size_t)(which * 2 + b) * NTOPK * 4;

  __shared__ float vals[QC];
  __shared__ float rv[4];
  __shared__ int   ri[4];
  const int tid = threadIdx.x;
  for (int j = tid; j < QC; j += 256) vals[j] = logits[j];
  __syncthreads();

  for (int it = 0; it < NTOPK; ++it) {
    float bv = -1e30f; int bi = 0x7fffffff;
    for (int j = tid; j < QC; j += 256) {
      float v = vals[j];
      if (v > bv) { bv = v; bi = j; }   // strict > keeps lowest index
    }
#pragma unroll
    for (int off = 32; off; off >>= 1) {
      float ov = __shfl_down(bv, off, 64);
      int   oi = __shfl_down(bi, off, 64);
      if (ov > bv || (ov == bv && oi < bi)) { bv = ov; bi = oi; }
    }
    if ((tid & 63) == 0) { rv[tid >> 6] = bv; ri[tid >> 6] = bi; }
    __syncthreads();
    if (tid == 0) {
      float v0 = rv[0]; int i0 = ri[0];
      for (int wq = 1; wq < 4; ++wq)
        if (rv[wq] > v0 || (rv[wq] == v0 && ri[wq] < i0)) { v0 = rv[wq]; i0 = ri[wq]; }
      vals[i0] = -1e30f;
      const int q = i0 / NC;
      const float cx = boxes[q*4+0], cy = boxes[q*4+1];
      const float w  = boxes[q*4+2], h  = boxes[q*4+3];
      const float hw = __fmul_rn(0.5f, w), hh = __fmul_rn(0.5f, h);
      outb[it*4+0] = __fmul_rn(__fsub_rn(cx, hw), 1024.0f);
      outb[it*4+1] = __fmul_rn(__fsub_rn(cy, hh), 1024.0f);
      outb[it*4+2] = __fmul_rn(__fadd_rn(cx, hw), 1024.0f);
      outb[it*4+3] = __fmul_rn(__fadd_rn(cy, hh), 1024.0f);
    }
    __syncthreads();
  }
}

// ---------------------------------------------------------------------------
// Kernel 2: bilinear 30x30 ROI crops -> X rows (interleaved layout) + pos_enc
// grid: 400 blocks, 256 threads. X row u = t*2 + b; pos_enc row = u % 100
// ---------------------------------------------------------------------------
__global__ __launch_bounds__(256) void roi_kernel(
    const float* __restrict__ g_samples, const float* __restrict__ a_samples,
    const float* __restrict__ boxes_px, const float* __restrict__ pos_enc,
    float* __restrict__ Xg, float* __restrict__ Xa) {
  const int which = blockIdx.x / 200;
  const int p     = blockIdx.x % 200;
  const int b = p / 100, t = p % 100;
  const float* img = (which ? a_samples : g_samples) + (size_t)b * 3 * IMGW * IMGW;
  const float* bx  = boxes_px + ((size_t)(which * 2 + b) * NTOPK + t) * 4;
  float* xrow = (which ? Xa : Xg) + (size_t)(t * 2 + b) * EMBED;
  const float* pe = pos_enc + (size_t)((t * 2 + b) % 100) * EMBED;

  __shared__ float s_wy[30], s_wx[30];
  __shared__ int   s_y0i[30], s_y1i[30], s_x0i[30], s_x1i[30];
  __shared__ float s_valid;

  const float x0 = rintf(bx[0]), y0 = rintf(bx[1]);
  const float x1 = rintf(bx[2]), y1 = rintf(bx[3]);
  const float w = __fsub_rn(x1, x0), h = __fsub_rn(y1, y0);
  const int tid = threadIdx.x;
  if (tid == 0) s_valid = (w > 0.0f && h > 0.0f) ? 1.0f : 0.0f;
  if (tid < 30) {
    const float g  = (float)tid + 0.5f;
    float sy = __fsub_rn(__fdiv_rn(__fmul_rn(g, h), 30.0f), 0.5f);
    const float hm1 = fmaxf(__fsub_rn(h, 1.0f), 0.0f);
    sy = fminf(fmaxf(sy, 0.0f), hm1);
    const float ay = __fadd_rn(y0, sy);
    const float yf = floorf(ay);
    s_wy[tid]  = __fsub_rn(ay, yf);
    s_y0i[tid] = (int)fminf(fmaxf(yf, 0.0f), 1023.0f);
    s_y1i[tid] = (int)fminf(fmaxf(yf + 1.0f, 0.0f), 1023.0f);
  } else if (tid >= 32 && tid < 62) {
    const int i = tid - 32;
    const float g = (float)i + 0.5f;
    float sx = __fsub_rn(__fdiv_rn(__fmul_rn(g, w), 30.0f), 0.5f);
    const float wm1 = fmaxf(__fsub_rn(w, 1.0f), 0.0f);
    sx = fminf(fmaxf(sx, 0.0f), wm1);
    const float ax = __fadd_rn(x0, sx);
    const float xf = floorf(ax);
    s_wx[i]  = __fsub_rn(ax, xf);
    s_x0i[i] = (int)fminf(fmaxf(xf, 0.0f), 1023.0f);
    s_x1i[i] = (int)fminf(fmaxf(xf + 1.0f, 0.0f), 1023.0f);
  }
  __syncthreads();
  const float valid = s_valid;
  for (int e = tid; e < EMBED; e += 256) {
    const int c = e / 900, pix = e % 900, py = pix / 30, px = pix % 30;
    const float* ic = img + (size_t)c * IMGW * IMGW;
    const int yi0 = s_y0i[py], yi1 = s_y1i[py], xi0 = s_x0i[px], xi1 = s_x1i[px];
    const float wy = s_wy[py], wx = s_wx[px];
    const float p00 = ic[yi0 * IMGW + xi0], p01 = ic[yi0 * IMGW + xi1];
    const float p10 = ic[yi1 * IMGW + xi0], p11 = ic[yi1 * IMGW + xi1];
    const float top = p00 * (1.0f - wx) + p01 * wx;
    const float bot = p10 * (1.0f - wx) + p11 * wx;
    const float val = top * (1.0f - wy) + bot * wy;
    xrow[e] = val * valid + pe[e];
  }
}

// ---------------------------------------------------------------------------
// Kernel 3a: zero the GEMM accumulators (ws is poisoned 0xAA)
// ---------------------------------------------------------------------------
__global__ void zero_kernel(float4* __restrict__ p, int n4) {
  const int i = blockIdx.x * blockDim.x + threadIdx.x;
  if (i < n4) p[i] = make_float4(0.f, 0.f, 0.f, 0.f);
}

// ---------------------------------------------------------------------------
// Kernel 3b: Y[200x2700] += X @ W^T. 128x128 tile, 8x8 micro, K split x3.
// grid (22, 2, 6): z = kc*2 + which; block 256 (16x16)
// ---------------------------------------------------------------------------
#define GBK 36
#define LSTR 132
__global__ __launch_bounds__(256) void gemm_kernel(
    const float* __restrict__ Xg, const float* __restrict__ Xa,
    const float* __restrict__ Wg, const float* __restrict__ Wa,
    float* __restrict__ Yg, float* __restrict__ Ya) {
  const int which = blockIdx.z & 1;
  const int kc    = blockIdx.z >> 1;          // 0..2, 900 K each
  const float* X = which ? Xa : Xg;
  const float* W = which ? Wa : Wg;
  float*       Y = which ? Ya : Yg;
  const int n0 = blockIdx.x * 128;
  const int m0 = blockIdx.y * 128;
  const int kbeg = kc * 900;

  __shared__ float Xs[GBK][LSTR];
  __shared__ float Ws[GBK][LSTR];
  const int tid = threadIdx.x;
  const int tx = tid & 15, ty = tid >> 4;
  float acc[2][2][4][4] = {};

  for (int t = 0; t < 25; ++t) {
    const int k0 = kbeg + t * GBK;
    // stage X tile: 128 rows x 36 k, 9 float4 per row
    for (int e = tid; e < 128 * 9; e += 256) {
      const int r = e / 9, c = e % 9;
      const int m = m0 + r;
      float4 v = make_float4(0.f, 0.f, 0.f, 0.f);
      if (m < 200) v = *(const float4*)&X[(size_t)m * EMBED + k0 + c * 4];
      Xs[c*4+0][r] = v.x; Xs[c*4+1][r] = v.y; Xs[c*4+2][r] = v.z; Xs[c*4+3][r] = v.w;
    }
    for (int e = tid; e < 128 * 9; e += 256) {
      const int r = e / 9, c = e % 9;
      const int n = n0 + r;
      float4 v = make_float4(0.f, 0.f, 0.f, 0.f);
      if (n < EMBED) v = *(const float4*)&W[(size_t)n * EMBED + k0 + c * 4];
      Ws[c*4+0][r] = v.x; Ws[c*4+1][r] = v.y; Ws[c*4+2][r] = v.z; Ws[c*4+3][r] = v.w;
    }
    __syncthreads();
#pragma unroll
    for (int k = 0; k < GBK; ++k) {
      const float4 a0 = *(const float4*)&Xs[k][ty * 4];
      const float4 a1 = *(const float4*)&Xs[k][64 + ty * 4];
      const float4 b0 = *(const float4*)&Ws[k][tx * 4];
      const float4 b1 = *(const float4*)&Ws[k][64 + tx * 4];
      const float av[2][4] = {{a0.x, a0.y, a0.z, a0.w}, {a1.x, a1.y, a1.z, a1.w}};
      const float bv[2][4] = {{b0.x, b0.y, b0.z, b0.w}, {b1.x, b1.y, b1.z, b1.w}};
#pragma unroll
      for (int im = 0; im < 2; ++im)
#pragma unroll
        for (int i = 0; i < 4; ++i)
#pragma unroll
          for (int jn = 0; jn < 2; ++jn)
#pragma unroll
            for (int j = 0; j < 4; ++j)
              acc[im][jn][i][j] += av[im][i] * bv[jn][j];
    }
    __syncthreads();
  }
#pragma unroll
  for (int im = 0; im < 2; ++im)
#pragma unroll
    for (int i = 0; i < 4; ++i) {
      const int m = m0 + im * 64 + ty * 4 + i;
      if (m < 200) {
#pragma unroll
        for (int jn = 0; jn < 2; ++jn)
#pragma unroll
          for (int j = 0; j < 4; ++j) {
            const int n = n0 + jn * 64 + tx * 4 + j;
            if (n < EMBED) unsafeAtomicAdd(&Y[(size_t)m * EMBED + n], acc[im][jn][i][j]);
          }
      }
    }
}

// ---------------------------------------------------------------------------
// Kernel 4a: sim partials. Block (kc, b2) computes simT[b2][k][q] for a
// 60-wide K chunk; both 100x60 tiles staged in LDS; 7x7 register microtile.
// part layout: [(kc*2+b2)][k][q], 45*2*100*100 floats.
// ---------------------------------------------------------------------------
#define SKC 60
__global__ __launch_bounds__(256) void sim_gemm_kernel(
    const float* __restrict__ Gt, const float* __restrict__ At,
    float* __restrict__ part) {
  const int kc = blockIdx.x;   // 0..44
  const int b2 = blockIdx.y;   // 0..1
  __shared__ float Gs[112][SKC];   // rows 100..111 uninit (never stored)
  __shared__ float As[112][SKC];
  const int tid = threadIdx.x;
  for (int e = tid; e < 100 * 15; e += 256) {
    const int r = e / 15, c = e % 15;
    const size_t src = (size_t)(b2 * 100 + r) * EMBED + kc * SKC + c * 4;
    *(float4*)&Gs[r][c * 4] = *(const float4*)&Gt[src];
    *(float4*)&As[r][c * 4] = *(const float4*)&At[src];
  }
  __syncthreads();
  const int tx = tid & 15, ty = tid >> 4;
  float acc[7][7] = {};
  for (int kd = 0; kd < SKC; kd += 4) {
    float4 g[7], a[7];
#pragma unroll
    for (int jq = 0; jq < 7; ++jq) g[jq] = *(const float4*)&Gs[tx + 16 * jq][kd];
#pragma unroll
    for (int ik = 0; ik < 7; ++ik) a[ik] = *(const float4*)&As[ty + 16 * ik][kd];
#pragma unroll
    for (int ik = 0; ik < 7; ++ik)
#pragma unroll
      for (int jq = 0; jq < 7; ++jq)
        acc[ik][jq] += a[ik].x * g[jq].x + a[ik].y * g[jq].y +
                       a[ik].z * g[jq].z + a[ik].w * g[jq].w;
  }
  float* pb = part + (size_t)(kc * 2 + b2) * 10000;
#pragma unroll
  for (int ik = 0; ik < 7; ++ik) {
    const int k = ty + 16 * ik;
    if (k < 100) {
#pragma unroll
      for (int jq = 0; jq < 7; ++jq) {
        const int q = tx + 16 * jq;
        if (q < 100) pb[k * 100 + q] = acc[ik][jq];
      }
    }
  }
}

// ---------------------------------------------------------------------------
// Kernel 4b: reduce partials over kc, softmax over q (dim 1), write out.
// One wave per (b2,k) column: grid 50 x 256.
// ---------------------------------------------------------------------------
__global__ __launch_bounds__(256) void softmax_kernel(
    const float* __restrict__ part, float* __restrict__ out) {
  const int wid  = (blockIdx.x << 2) | (threadIdx.x >> 6);  // 0..199
  const int lane = threadIdx.x & 63;
  const int b2 = wid / 100, k = wid % 100;
  float s0 = 0.f, s1 = 0.f;
  for (int kc = 0; kc < 45; ++kc) {
    const float* p = part + ((size_t)(kc * 2 + b2) * 100 + k) * 100;
    s0 += p[lane];
    if (lane < 36) s1 += p[lane + 64];
  }
  const float scale = sqrtf(384.0f);
  const float v0 = s0 / scale;
  const float v1 = s1 / scale;
  float m = (lane < 36) ? fmaxf(v0, v1) : v0;
#pragma unroll
  for (int off = 32; off; off >>= 1) m = fmaxf(m, __shfl_down(m, off, 64));
  m = __shfl(m, 0, 64);
  const float e0 = expf(v0 - m);
  const float e1 = (lane < 36) ? expf(v1 - m) : 0.f;
  float d = e0 + e1;
#pragma unroll
  for (int off = 32; off; off >>= 1) d += __shfl_down(d, off, 64);
  d = __shfl(d, 0, 64);
  out[((size_t)b2 * 100 + lane) * 100 + k] = e0 / d;
  if (lane < 36) out[((size_t)b2 * 100 + lane + 64) * 100 + k] = e1 / d;
}

// ---------------------------------------------------------------------------
extern "C" void kernel_launch(void* const* d_in, const int* in_sizes, int n_in,
                              void* d_out, int out_size, void* d_ws, size_t ws_size,
                              hipStream_t stream) {
  const float* g_samples = (const float*)d_in[0];
  const float* a_samples = (const float*)d_in[1];
  const float* g_logits  = (const float*)d_in[2];
  const float* a_logits  = (const float*)d_in[3];
  const float* g_boxes   = (const float*)d_in[4];
  const float* a_boxes   = (const float*)d_in[5];
  const float* W_ground  = (const float*)d_in[6];
  const float* W_aerial  = (const float*)d_in[7];
  const float* pos_enc   = (const float*)d_in[8];
  float* out = (float*)d_out;
  float* ws  = (float*)d_ws;

  const size_t R = 540672;             // 200*2700 rounded up
  float* boxes_px = ws;                // 1600 floats
  float* Xg   = ws + 2048;
  float* Xa   = Xg + R;
  float* Gt   = Xa + R;
  float* At   = Gt + R;
  float* part = At + R;                // 45*2*100*100 = 900000 floats

  topk_boxes_kernel<<<4, 256, 0, stream>>>(g_logits, a_logits, g_boxes, a_boxes, boxes_px);
  roi_kernel<<<400, 256, 0, stream>>>(g_samples, a_samples, boxes_px, pos_enc, Xg, Xa);
  {
    const int n4 = (int)(2 * R / 4);   // zero Gt and At (contiguous)
    zero_kernel<<<(n4 + 255) / 256, 256, 0, stream>>>((float4*)Gt, n4);
  }
  gemm_kernel<<<dim3(22, 2, 6), 256, 0, stream>>>(Xg, Xa, W_ground, W_aerial, Gt, At);
  sim_gemm_kernel<<<dim3(45, 2), 256, 0, stream>>>(Gt, At, part);
  softmax_kernel<<<50, 256, 0, stream>>>(part, out);
}

// Round 3
// 349.979 us; speedup vs baseline: 2.4179x; 1.7213x over previous
//
#include <hip/hip_runtime.h>
#include <math.h>

#define NTOPK 100
#define QC    6000
#define NC    20
#define EMBED 2700
#define IMGW  1024

typedef __attribute__((ext_vector_type(8))) short short8;
typedef __attribute__((ext_vector_type(4))) float f32x4;

__device__ inline short f32_bf16_rne(float x) {
  const unsigned u = __float_as_uint(x);
  return (short)((u + 0x7fffu + ((u >> 16) & 1u)) >> 16);
}

// ---------------------------------------------------------------------------
// Kernel 1: radix-select top-100 -> xyxy pixel boxes. grid 4, block 256.
// key = order-flipped f32 bits of logit (sigmoid is monotonic).
// ---------------------------------------------------------------------------
__global__ __launch_bounds__(256) void topk_boxes_kernel(
    const float* __restrict__ g_logits, const float* __restrict__ a_logits,
    const float* __restrict__ g_boxes,  const float* __restrict__ a_boxes,
    float* __restrict__ boxes_px /* [2][2][100][4] */) {
  const int which = blockIdx.x >> 1;
  const int b     = blockIdx.x & 1;
  const float* logits = (which ? a_logits : g_logits) + b * QC;
  const float* boxes  = (which ? a_boxes  : g_boxes)  + b * 300 * 4;
  float* outb = boxes_px + (size_t)(which * 2 + b) * NTOPK * 4;

  __shared__ unsigned keys[QC];
  __shared__ int hist[4096];
  __shared__ int csum[256];
  __shared__ unsigned long long cand[256];
  __shared__ int s_cnt, s_bstar;

  const int tid = threadIdx.x;
  for (int i = tid; i < 4096; i += 256) hist[i] = 0;
  if (tid == 0) s_cnt = 0;
  __syncthreads();
  for (int j = tid; j < QC; j += 256) {
    const unsigned u = __float_as_uint(logits[j]);
    const unsigned k = u ^ ((u >> 31) ? 0xFFFFFFFFu : 0x80000000u);
    keys[j] = k;
    atomicAdd(&hist[k >> 20], 1);
  }
  __syncthreads();
  int cs = 0;
#pragma unroll
  for (int i = 0; i < 16; ++i) cs += hist[tid * 16 + i];
  csum[tid] = cs;
  __syncthreads();
  if (tid == 0) {
    int acc = 0, c = 255;
    for (; c > 0; --c) { if (acc + csum[c] >= NTOPK) break; acc += csum[c]; }
    int bstar = c * 16;
    for (int bb = c * 16 + 15; bb >= c * 16; --bb) {
      if (acc + hist[bb] >= NTOPK) { bstar = bb; break; }
      acc += hist[bb];
    }
    s_bstar = bstar;
  }
  __syncthreads();
  const unsigned bstar = (unsigned)s_bstar;
  for (int j = tid; j < QC; j += 256) {
    if ((keys[j] >> 20) >= bstar) {
      const int pos = atomicAdd(&s_cnt, 1);
      if (pos < 256)
        cand[pos] = (((unsigned long long)(~keys[j])) << 13) | (unsigned)j;
    }
  }
  __syncthreads();
  const int cnt = s_cnt < 256 ? s_cnt : 256;
  if (tid >= cnt) cand[tid] = ~0ULL;
  __syncthreads();
  // bitonic sort 256 ascending by ((~key)<<13 | idx)  == (value desc, idx asc)
  for (int kk = 2; kk <= 256; kk <<= 1) {
    for (int j = kk >> 1; j > 0; j >>= 1) {
      const int p = tid ^ j;
      if (p > tid) {
        const unsigned long long x = cand[tid], y = cand[p];
        const bool up = ((tid & kk) == 0);
        if ((x > y) == up) { cand[tid] = y; cand[p] = x; }
      }
      __syncthreads();
    }
  }
  if (tid < NTOPK) {
    const int idx = (int)(cand[tid] & 8191ULL);
    const int q = idx / NC;
    const float cx = boxes[q*4+0], cy = boxes[q*4+1];
    const float w  = boxes[q*4+2], h  = boxes[q*4+3];
    const float hw = __fmul_rn(0.5f, w), hh = __fmul_rn(0.5f, h);
    outb[tid*4+0] = __fmul_rn(__fsub_rn(cx, hw), 1024.0f);
    outb[tid*4+1] = __fmul_rn(__fsub_rn(cy, hh), 1024.0f);
    outb[tid*4+2] = __fmul_rn(__fadd_rn(cx, hw), 1024.0f);
    outb[tid*4+3] = __fmul_rn(__fadd_rn(cy, hh), 1024.0f);
  }
}

// ---------------------------------------------------------------------------
// Kernel 2: bilinear ROI crops, one block per (which,b,t,channel). grid 1200.
// X row u = t*2 + b; pos_enc row = u % 100
// ---------------------------------------------------------------------------
__global__ __launch_bounds__(256) void roi_kernel(
    const float* __restrict__ g_samples, const float* __restrict__ a_samples,
    const float* __restrict__ boxes_px, const float* __restrict__ pos_enc,
    float* __restrict__ Xg, float* __restrict__ Xa) {
  const int bi = blockIdx.x;
  const int which = bi / 600;
  const int rem = bi % 600;
  const int p = rem / 3, c = rem % 3;
  const int b = p / 100, t = p % 100;
  const float* ic = (which ? a_samples : g_samples)
                    + ((size_t)b * 3 + c) * IMGW * IMGW;
  const float* bx = boxes_px + ((size_t)(which * 2 + b) * NTOPK + t) * 4;
  float* xrow = (which ? Xa : Xg) + (size_t)(t * 2 + b) * EMBED + c * 900;
  const float* pe = pos_enc + (size_t)((t * 2 + b) % 100) * EMBED + c * 900;

  __shared__ float s_wy[30], s_wx[30];
  __shared__ int   s_y0i[30], s_y1i[30], s_x0i[30], s_x1i[30];
  __shared__ float s_valid;

  const float x0 = rintf(bx[0]), y0 = rintf(bx[1]);
  const float x1 = rintf(bx[2]), y1 = rintf(bx[3]);
  const float w = __fsub_rn(x1, x0), h = __fsub_rn(y1, y0);
  const int tid = threadIdx.x;
  if (tid == 0) s_valid = (w > 0.0f && h > 0.0f) ? 1.0f : 0.0f;
  if (tid < 30) {
    const float g  = (float)tid + 0.5f;
    float sy = __fsub_rn(__fdiv_rn(__fmul_rn(g, h), 30.0f), 0.5f);
    const float hm1 = fmaxf(__fsub_rn(h, 1.0f), 0.0f);
    sy = fminf(fmaxf(sy, 0.0f), hm1);
    const float ay = __fadd_rn(y0, sy);
    const float yf = floorf(ay);
    s_wy[tid]  = __fsub_rn(ay, yf);
    s_y0i[tid] = (int)fminf(fmaxf(yf, 0.0f), 1023.0f);
    s_y1i[tid] = (int)fminf(fmaxf(yf + 1.0f, 0.0f), 1023.0f);
  } else if (tid >= 32 && tid < 62) {
    const int i = tid - 32;
    const float g = (float)i + 0.5f;
    float sx = __fsub_rn(__fdiv_rn(__fmul_rn(g, w), 30.0f), 0.5f);
    const float wm1 = fmaxf(__fsub_rn(w, 1.0f), 0.0f);
    sx = fminf(fmaxf(sx, 0.0f), wm1);
    const float ax = __fadd_rn(x0, sx);
    const float xf = floorf(ax);
    s_wx[i]  = __fsub_rn(ax, xf);
    s_x0i[i] = (int)fminf(fmaxf(xf, 0.0f), 1023.0f);
    s_x1i[i] = (int)fminf(fmaxf(xf + 1.0f, 0.0f), 1023.0f);
  }
  __syncthreads();
  const float valid = s_valid;
  for (int pix = tid; pix < 900; pix += 256) {
    const int py = pix / 30, px = pix % 30;
    const int yi0 = s_y0i[py], yi1 = s_y1i[py], xi0 = s_x0i[px], xi1 = s_x1i[px];
    const float wy = s_wy[py], wx = s_wx[px];
    const float p00 = ic[yi0 * IMGW + xi0], p01 = ic[yi0 * IMGW + xi1];
    const float p10 = ic[yi1 * IMGW + xi0], p11 = ic[yi1 * IMGW + xi1];
    const float top = p00 * (1.0f - wx) + p01 * wx;
    const float bot = p10 * (1.0f - wx) + p11 * wx;
    const float val = top * (1.0f - wy) + bot * wy;
    xrow[pix] = val * valid + pe[pix];
  }
}

// ---------------------------------------------------------------------------
// Kernel 3: Y[200x2700] = X @ W^T via bf16 hi/lo split MFMA (3 products).
// BM=64, BN=128, BK=64; grid (22, 4, 2); block 256 (4 waves, 2x2).
// LDS tiles XOR-swizzled: slot = kchunk ^ (row&7)  (rows are 128 B).
// ---------------------------------------------------------------------------
__global__ __launch_bounds__(256) void gemm_kernel(
    const float* __restrict__ Xg, const float* __restrict__ Xa,
    const float* __restrict__ Wg, const float* __restrict__ Wa,
    float* __restrict__ Yg, float* __restrict__ Ya) {
  const int which = blockIdx.z;
  const float* X = which ? Xa : Xg;
  const float* W = which ? Wa : Wg;
  float*       Y = which ? Ya : Yg;
  const int n0 = blockIdx.x * 128;
  const int m0 = blockIdx.y * 64;
  const int mrows = (200 - m0) < 64 ? (200 - m0) : 64;
  const int nrows = (EMBED - n0) < 128 ? (EMBED - n0) : 128;

  __shared__ short Ah[64 * 64], Al[64 * 64];
  __shared__ short Bh[128 * 64], Bl[128 * 64];

  const int tid = threadIdx.x;
  const int lane = tid & 63, wid = tid >> 6;
  const int wr = wid >> 1, wc = wid & 1;
  const int lr = lane & 15, lg = lane >> 4;

  f32x4 acc[2][4] = {};

  for (int t = 0; t < 43; ++t) {
    const int k0 = t * 64;
    // ---- stage A: 64 rows x 8 chunks of 8 ----
    for (int cid = tid; cid < 512; cid += 256) {
      const int row = cid >> 3, kc = cid & 7;
      const int k = k0 + kc * 8;
      float v[8];
      const bool rv = row < mrows;
      if (rv && k + 8 <= EMBED) {
        const float4* s = (const float4*)&X[(size_t)(m0 + row) * EMBED + k];
        const float4 v0 = s[0], v1 = s[1];
        v[0]=v0.x; v[1]=v0.y; v[2]=v0.z; v[3]=v0.w;
        v[4]=v1.x; v[5]=v1.y; v[6]=v1.z; v[7]=v1.w;
      } else {
#pragma unroll
        for (int e = 0; e < 8; ++e)
          v[e] = (rv && k + e < EMBED) ? X[(size_t)(m0 + row) * EMBED + k + e] : 0.f;
      }
      short8 hv, lv;
#pragma unroll
      for (int e = 0; e < 8; ++e) {
        const short hb = f32_bf16_rne(v[e]);
        const float hf = __uint_as_float(((unsigned)(unsigned short)hb) << 16);
        hv[e] = hb;
        lv[e] = f32_bf16_rne(v[e] - hf);
      }
      const int off = row * 64 + ((kc ^ (row & 7)) << 3);
      *(short8*)&Ah[off] = hv;
      *(short8*)&Al[off] = lv;
    }
    // ---- stage B: 128 rows x 8 chunks ----
    for (int cid = tid; cid < 1024; cid += 256) {
      const int row = cid >> 3, kc = cid & 7;
      const int k = k0 + kc * 8;
      float v[8];
      const bool rv = row < nrows;
      if (rv && k + 8 <= EMBED) {
        const float4* s = (const float4*)&W[(size_t)(n0 + row) * EMBED + k];
        const float4 v0 = s[0], v1 = s[1];
        v[0]=v0.x; v[1]=v0.y; v[2]=v0.z; v[3]=v0.w;
        v[4]=v1.x; v[5]=v1.y; v[6]=v1.z; v[7]=v1.w;
      } else {
#pragma unroll
        for (int e = 0; e < 8; ++e)
          v[e] = (rv && k + e < EMBED) ? W[(size_t)(n0 + row) * EMBED + k + e] : 0.f;
      }
      short8 hv, lv;
#pragma unroll
      for (int e = 0; e < 8; ++e) {
        const short hb = f32_bf16_rne(v[e]);
        const float hf = __uint_as_float(((unsigned)(unsigned short)hb) << 16);
        hv[e] = hb;
        lv[e] = f32_bf16_rne(v[e] - hf);
      }
      const int off = row * 64 + ((kc ^ (row & 7)) << 3);
      *(short8*)&Bh[off] = hv;
      *(short8*)&Bl[off] = lv;
    }
    __syncthreads();
#pragma unroll
    for (int ks = 0; ks < 2; ++ks) {
      short8 a_h[2], a_l[2], b_h[4], b_l[4];
#pragma unroll
      for (int mr = 0; mr < 2; ++mr) {
        const int row = wr * 32 + mr * 16 + lr;
        const int off = row * 64 + (((ks * 4 + lg) ^ (row & 7)) << 3);
        a_h[mr] = *(const short8*)&Ah[off];
        a_l[mr] = *(const short8*)&Al[off];
      }
#pragma unroll
      for (int nr = 0; nr < 4; ++nr) {
        const int row = wc * 64 + nr * 16 + lr;
        const int off = row * 64 + (((ks * 4 + lg) ^ (row & 7)) << 3);
        b_h[nr] = *(const short8*)&Bh[off];
        b_l[nr] = *(const short8*)&Bl[off];
      }
#pragma unroll
      for (int mr = 0; mr < 2; ++mr)
#pragma unroll
        for (int nr = 0; nr < 4; ++nr) {
          acc[mr][nr] = __builtin_amdgcn_mfma_f32_16x16x32_bf16(a_h[mr], b_h[nr], acc[mr][nr], 0, 0, 0);
          acc[mr][nr] = __builtin_amdgcn_mfma_f32_16x16x32_bf16(a_h[mr], b_l[nr], acc[mr][nr], 0, 0, 0);
          acc[mr][nr] = __builtin_amdgcn_mfma_f32_16x16x32_bf16(a_l[mr], b_h[nr], acc[mr][nr], 0, 0, 0);
        }
    }
    __syncthreads();
  }
  // epilogue: D col = lane&15, row = (lane>>4)*4 + r
#pragma unroll
  for (int mr = 0; mr < 2; ++mr)
#pragma unroll
    for (int nr = 0; nr < 4; ++nr) {
      const int rloc = wr * 32 + mr * 16 + lg * 4;
      const int nloc = wc * 64 + nr * 16 + lr;
      if (nloc < nrows) {
#pragma unroll
        for (int r = 0; r < 4; ++r) {
          if (rloc + r < mrows)
            Y[(size_t)(m0 + rloc + r) * EMBED + n0 + nloc] = acc[mr][nr][r];
        }
      }
    }
}

// ---------------------------------------------------------------------------
// Kernel 4a: sim partials. Block (kc, b2): simT for a 60-wide K chunk.
// ---------------------------------------------------------------------------
#define SKC 60
__global__ __launch_bounds__(256) void sim_gemm_kernel(
    const float* __restrict__ Gt, const float* __restrict__ At,
    float* __restrict__ part) {
  const int kc = blockIdx.x;   // 0..44
  const int b2 = blockIdx.y;   // 0..1
  __shared__ float Gs[112][SKC];
  __shared__ float As[112][SKC];
  const int tid = threadIdx.x;
  for (int e = tid; e < 100 * 15; e += 256) {
    const int r = e / 15, c = e % 15;
    const size_t src = (size_t)(b2 * 100 + r) * EMBED + kc * SKC + c * 4;
    *(float4*)&Gs[r][c * 4] = *(const float4*)&Gt[src];
    *(float4*)&As[r][c * 4] = *(const float4*)&At[src];
  }
  __syncthreads();
  const int tx = tid & 15, ty = tid >> 4;
  float acc[7][7] = {};
  for (int kd = 0; kd < SKC; kd += 4) {
    float4 g[7], a[7];
#pragma unroll
    for (int jq = 0; jq < 7; ++jq) g[jq] = *(const float4*)&Gs[tx + 16 * jq][kd];
#pragma unroll
    for (int ik = 0; ik < 7; ++ik) a[ik] = *(const float4*)&As[ty + 16 * ik][kd];
#pragma unroll
    for (int ik = 0; ik < 7; ++ik)
#pragma unroll
      for (int jq = 0; jq < 7; ++jq)
        acc[ik][jq] += a[ik].x * g[jq].x + a[ik].y * g[jq].y +
                       a[ik].z * g[jq].z + a[ik].w * g[jq].w;
  }
  float* pb = part + (size_t)(kc * 2 + b2) * 10000;
#pragma unroll
  for (int ik = 0; ik < 7; ++ik) {
    const int k = ty + 16 * ik;
    if (k < 100) {
#pragma unroll
      for (int jq = 0; jq < 7; ++jq) {
        const int q = tx + 16 * jq;
        if (q < 100) pb[k * 100 + q] = acc[ik][jq];
      }
    }
  }
}

// ---------------------------------------------------------------------------
// Kernel 4b: reduce over kc, softmax over q (dim 1), write out.
// ---------------------------------------------------------------------------
__global__ __launch_bounds__(256) void softmax_kernel(
    const float* __restrict__ part, float* __restrict__ out) {
  const int wid  = (blockIdx.x << 2) | (threadIdx.x >> 6);  // 0..199
  const int lane = threadIdx.x & 63;
  const int b2 = wid / 100, k = wid % 100;
  float s0 = 0.f, s1 = 0.f;
  for (int kc = 0; kc < 45; ++kc) {
    const float* p = part + ((size_t)(kc * 2 + b2) * 100 + k) * 100;
    s0 += p[lane];
    if (lane < 36) s1 += p[lane + 64];
  }
  const float scale = sqrtf(384.0f);
  const float v0 = s0 / scale;
  const float v1 = s1 / scale;
  float m = (lane < 36) ? fmaxf(v0, v1) : v0;
#pragma unroll
  for (int off = 32; off; off >>= 1) m = fmaxf(m, __shfl_down(m, off, 64));
  m = __shfl(m, 0, 64);
  const float e0 = expf(v0 - m);
  const float e1 = (lane < 36) ? expf(v1 - m) : 0.f;
  float d = e0 + e1;
#pragma unroll
  for (int off = 32; off; off >>= 1) d += __shfl_down(d, off, 64);
  d = __shfl(d, 0, 64);
  out[((size_t)b2 * 100 + lane) * 100 + k] = e0 / d;
  if (lane < 36) out[((size_t)b2 * 100 + lane + 64) * 100 + k] = e1 / d;
}

// ---------------------------------------------------------------------------
extern "C" void kernel_launch(void* const* d_in, const int* in_sizes, int n_in,
                              void* d_out, int out_size, void* d_ws, size_t ws_size,
                              hipStream_t stream) {
  const float* g_samples = (const float*)d_in[0];
  const float* a_samples = (const float*)d_in[1];
  const float* g_logits  = (const float*)d_in[2];
  const float* a_logits  = (const float*)d_in[3];
  const float* g_boxes   = (const float*)d_in[4];
  const float* a_boxes   = (const float*)d_in[5];
  const float* W_ground  = (const float*)d_in[6];
  const float* W_aerial  = (const float*)d_in[7];
  const float* pos_enc   = (const float*)d_in[8];
  float* out = (float*)d_out;
  float* ws  = (float*)d_ws;

  const size_t R = 540672;             // 200*2700 rounded up
  float* boxes_px = ws;                // 1600 floats
  float* Xg   = ws + 2048;
  float* Xa   = Xg + R;
  float* Gt   = Xa + R;
  float* At   = Gt + R;
  float* part = At + R;                // 45*2*100*100 = 900000 floats

  topk_boxes_kernel<<<4, 256, 0, stream>>>(g_logits, a_logits, g_boxes, a_boxes, boxes_px);
  roi_kernel<<<1200, 256, 0, stream>>>(g_samples, a_samples, boxes_px, pos_enc, Xg, Xa);
  gemm_kernel<<<dim3(22, 4, 2), 256, 0, stream>>>(Xg, Xa, W_ground, W_aerial, Gt, At);
  sim_gemm_kernel<<<dim3(45, 2), 256, 0, stream>>>(Gt, At, part);
  softmax_kernel<<<50, 256, 0, stream>>>(part, out);
}

// Round 4
// 236.567 us; speedup vs baseline: 3.5771x; 1.4794x over previous
//
#include <hip/hip_runtime.h>
#include <math.h>

#define NTOPK 100
#define QC    6000
#define NC    20
#define EMBED 2700
#define IMGW  1024
#define XSTR  2704          // padded short stride for Xh/Xl rows
#define YPLANE 1080000      // 2*200*2700 floats per kc partial plane

typedef __attribute__((ext_vector_type(8))) short short8;
typedef __attribute__((ext_vector_type(4))) float f32x4;

__device__ inline short f32_bf16_rne(float x) {
  const unsigned u = __float_as_uint(x);
  return (short)((u + 0x7fffu + ((u >> 16) & 1u)) >> 16);
}
__device__ inline void split_hl(float x, short& h, short& l) {
  h = f32_bf16_rne(x);
  const float hf = __uint_as_float(((unsigned)(unsigned short)h) << 16);
  l = f32_bf16_rne(x - hf);
}
__device__ inline short8 zero8() {
  short8 z;
#pragma unroll
  for (int i = 0; i < 8; ++i) z[i] = 0;
  return z;
}

// ---------------------------------------------------------------------------
// Kernel 1: radix-select top-100 -> xyxy pixel boxes. grid 4, block 256.
// Parallel suffix scan + rank-by-count (no serial LDS scans, no bitonic).
// ---------------------------------------------------------------------------
__global__ __launch_bounds__(256) void topk_boxes_kernel(
    const float* __restrict__ g_logits, const float* __restrict__ a_logits,
    const float* __restrict__ g_boxes,  const float* __restrict__ a_boxes,
    float* __restrict__ boxes_px /* [2][2][100][4] */) {
  const int which = blockIdx.x >> 1;
  const int b     = blockIdx.x & 1;
  const float* logits = (which ? a_logits : g_logits) + b * QC;
  const float* boxes  = (which ? a_boxes  : g_boxes)  + b * 300 * 4;
  float* outb = boxes_px + (size_t)(which * 2 + b) * NTOPK * 4;

  __shared__ unsigned keys[QC];
  __shared__ int hist[4096];
  __shared__ int suf[257];
  __shared__ unsigned long long cand[256];
  __shared__ int s_cnt, s_bstar;

  const int tid = threadIdx.x;
  for (int i = tid; i < 4096; i += 256) hist[i] = 0;
  if (tid == 0) s_cnt = 0;
  __syncthreads();
  for (int j = tid; j < QC; j += 256) {
    const unsigned u = __float_as_uint(logits[j]);
    const unsigned k = u ^ ((u >> 31) ? 0xFFFFFFFFu : 0x80000000u);
    keys[j] = k;
    atomicAdd(&hist[k >> 20], 1);
  }
  __syncthreads();
  int cs = 0;
#pragma unroll
  for (int i = 0; i < 16; ++i) cs += hist[tid * 16 + i];
  suf[tid] = cs;
  if (tid == 0) suf[256] = 0;
  __syncthreads();
  // Hillis-Steele suffix sum over 256 coarse bins
  for (int d = 1; d < 256; d <<= 1) {
    const int v = (tid + d < 256) ? suf[tid + d] : 0;
    __syncthreads();
    suf[tid] += v;
    __syncthreads();
  }
  // unique coarse bin c: suf[c] >= K > suf[c+1]; that thread does the fine scan
  if (suf[tid] >= NTOPK && (tid == 255 || suf[tid + 1] < NTOPK)) {
    int acc = suf[tid + 1];
    int bstar = tid * 16;
    for (int bb = tid * 16 + 15; bb >= tid * 16; --bb) {
      if (acc + hist[bb] >= NTOPK) { bstar = bb; break; }
      acc += hist[bb];
    }
    s_bstar = bstar;
  }
  __syncthreads();
  const unsigned bstar = (unsigned)s_bstar;
  for (int j = tid; j < QC; j += 256) {
    if ((keys[j] >> 20) >= bstar) {
      const int pos = atomicAdd(&s_cnt, 1);
      if (pos < 256)
        cand[pos] = (((unsigned long long)(~keys[j])) << 13) | (unsigned)j;
    }
  }
  __syncthreads();
  const int cnt = s_cnt < 256 ? s_cnt : 256;
  if (tid < cnt) {
    const unsigned long long me = cand[tid];
    int rank = 0;
    for (int j = 0; j < cnt; ++j) rank += (cand[j] < me);
    if (rank < NTOPK) {
      const int idx = (int)(me & 8191ULL);
      const int q = idx / NC;
      const float cx = boxes[q*4+0], cy = boxes[q*4+1];
      const float w  = boxes[q*4+2], h  = boxes[q*4+3];
      const float hw = __fmul_rn(0.5f, w), hh = __fmul_rn(0.5f, h);
      outb[rank*4+0] = __fmul_rn(__fsub_rn(cx, hw), 1024.0f);
      outb[rank*4+1] = __fmul_rn(__fsub_rn(cy, hh), 1024.0f);
      outb[rank*4+2] = __fmul_rn(__fadd_rn(cx, hw), 1024.0f);
      outb[rank*4+3] = __fmul_rn(__fadd_rn(cy, hh), 1024.0f);
    }
  }
}

// ---------------------------------------------------------------------------
// Kernel 2: bilinear ROI crops -> bf16 hi/lo X rows (+pos_enc), stride XSTR.
// grid 1200: (which, b, t, channel). X row u = t*2 + b; pe row = u % 100.
// ---------------------------------------------------------------------------
__global__ __launch_bounds__(256) void roi_kernel(
    const float* __restrict__ g_samples, const float* __restrict__ a_samples,
    const float* __restrict__ boxes_px, const float* __restrict__ pos_enc,
    short* __restrict__ Xgh, short* __restrict__ Xgl,
    short* __restrict__ Xah, short* __restrict__ Xal) {
  const int bi = blockIdx.x;
  const int which = bi / 600;
  const int rem = bi % 600;
  const int p = rem / 3, c = rem % 3;
  const int b = p / 100, t = p % 100;
  const int u = t * 2 + b;
  const float* ic = (which ? a_samples : g_samples)
                    + ((size_t)b * 3 + c) * IMGW * IMGW;
  const float* bx = boxes_px + ((size_t)(which * 2 + b) * NTOPK + t) * 4;
  short* xh = (which ? Xah : Xgh) + (size_t)u * XSTR + c * 900;
  short* xl = (which ? Xal : Xgl) + (size_t)u * XSTR + c * 900;
  const float* pe = pos_enc + (size_t)(u % 100) * EMBED + c * 900;

  __shared__ float s_wy[30], s_wx[30];
  __shared__ int   s_y0i[30], s_y1i[30], s_x0i[30], s_x1i[30];
  __shared__ float s_valid;

  const float x0 = rintf(bx[0]), y0 = rintf(bx[1]);
  const float x1 = rintf(bx[2]), y1 = rintf(bx[3]);
  const float w = __fsub_rn(x1, x0), h = __fsub_rn(y1, y0);
  const int tid = threadIdx.x;
  if (tid == 0) s_valid = (w > 0.0f && h > 0.0f) ? 1.0f : 0.0f;
  if (tid < 30) {
    const float g  = (float)tid + 0.5f;
    float sy = __fsub_rn(__fdiv_rn(__fmul_rn(g, h), 30.0f), 0.5f);
    const float hm1 = fmaxf(__fsub_rn(h, 1.0f), 0.0f);
    sy = fminf(fmaxf(sy, 0.0f), hm1);
    const float ay = __fadd_rn(y0, sy);
    const float yf = floorf(ay);
    s_wy[tid]  = __fsub_rn(ay, yf);
    s_y0i[tid] = (int)fminf(fmaxf(yf, 0.0f), 1023.0f);
    s_y1i[tid] = (int)fminf(fmaxf(yf + 1.0f, 0.0f), 1023.0f);
  } else if (tid >= 32 && tid < 62) {
    const int i = tid - 32;
    const float g = (float)i + 0.5f;
    float sx = __fsub_rn(__fdiv_rn(__fmul_rn(g, w), 30.0f), 0.5f);
    const float wm1 = fmaxf(__fsub_rn(w, 1.0f), 0.0f);
    sx = fminf(fmaxf(sx, 0.0f), wm1);
    const float ax = __fadd_rn(x0, sx);
    const float xf = floorf(ax);
    s_wx[i]  = __fsub_rn(ax, xf);
    s_x0i[i] = (int)fminf(fmaxf(xf, 0.0f), 1023.0f);
    s_x1i[i] = (int)fminf(fmaxf(xf + 1.0f, 0.0f), 1023.0f);
  }
  __syncthreads();
  const float valid = s_valid;
  for (int pix = tid; pix < 900; pix += 256) {
    const int py = pix / 30, px = pix % 30;
    const int yi0 = s_y0i[py], yi1 = s_y1i[py], xi0 = s_x0i[px], xi1 = s_x1i[px];
    const float wy = s_wy[py], wx = s_wx[px];
    const float p00 = ic[yi0 * IMGW + xi0], p01 = ic[yi0 * IMGW + xi1];
    const float p10 = ic[yi1 * IMGW + xi0], p11 = ic[yi1 * IMGW + xi1];
    const float top = p00 * (1.0f - wx) + p01 * wx;
    const float bot = p10 * (1.0f - wx) + p11 * wx;
    const float val = top * (1.0f - wy) + bot * wy;
    const float x = val * valid + pe[pix];
    short hb, lb;
    split_hl(x, hb, lb);
    xh[pix] = hb;
    xl[pix] = lb;
  }
  // zero the 4 pad shorts of each row once (c==2 owns cols 1800..2699)
  if (c == 2 && tid < 4) {
    short* bh = (which ? Xah : Xgh) + (size_t)u * XSTR;
    short* bl = (which ? Xal : Xgl) + (size_t)u * XSTR;
    bh[2700 + tid] = 0;
    bl[2700 + tid] = 0;
  }
}

// ---------------------------------------------------------------------------
// Kernel 3: Ypart[kc] = X[0:256 pad] @ W^T (K chunk kc) via bf16 hi/lo MFMA.
// BM=256 (all M), BN=64, BK=64; grid (43, 4 kc, 2 which); 4 waves.
// Wave w owns rows w*64..w*64+63, all 64 cols. LDS XOR-swizzled 16B slots.
// ---------------------------------------------------------------------------
__global__ __launch_bounds__(256) void gemm_kernel(
    const short* __restrict__ Xgh, const short* __restrict__ Xgl,
    const short* __restrict__ Xah, const short* __restrict__ Xal,
    const float* __restrict__ Wg, const float* __restrict__ Wa,
    float* __restrict__ Ypart) {
  const int which = blockIdx.z;
  const int kc    = blockIdx.y;
  const short* Xh = which ? Xah : Xgh;
  const short* Xl = which ? Xal : Xgl;
  const float* W  = which ? Wa  : Wg;
  float* Y = Ypart + (size_t)kc * YPLANE + (size_t)which * 540000;
  const int n0 = blockIdx.x * 64;
  const int kbeg = kc * 704;
  const int ksteps = (kc < 3) ? 11 : 10;

  __shared__ short Ah[256 * 64], Al[256 * 64];
  __shared__ short Bh[64 * 64],  Bl[64 * 64];

  const int tid = threadIdx.x;
  const int lane = tid & 63, wid = tid >> 6;
  const int lr = lane & 15, lg = lane >> 4;

  f32x4 acc[4][4] = {};

  for (int t = 0; t < ksteps; ++t) {
    const int k0 = kbeg + t * 64;
    // ---- stage A: 256 rows x 8 chunks of 8 shorts (pure copy) ----
#pragma unroll
    for (int it = 0; it < 8; ++it) {
      const int cid = it * 256 + tid;
      const int row = cid >> 3, s8 = cid & 7;
      const int k = k0 + s8 * 8;
      short8 hv = zero8(), lv = zero8();
      if (row < 200 && k < EMBED) {
        hv = *(const short8*)&Xh[(size_t)row * XSTR + k];
        lv = *(const short8*)&Xl[(size_t)row * XSTR + k];
      }
      const int off = (row << 6) + ((s8 ^ (row & 7)) << 3);
      *(short8*)&Ah[off] = hv;
      *(short8*)&Al[off] = lv;
    }
    // ---- stage B: 64 rows x 8 chunks, f32 -> hi/lo convert ----
#pragma unroll
    for (int it = 0; it < 2; ++it) {
      const int cid = it * 256 + tid;
      const int row = cid >> 3, s8 = cid & 7;
      const int n = n0 + row;
      const int k = k0 + s8 * 8;
      float v[8];
#pragma unroll
      for (int e = 0; e < 8; ++e) v[e] = 0.0f;
      if (n < EMBED) {
        if (k + 8 <= EMBED) {
          const float4* s = (const float4*)&W[(size_t)n * EMBED + k];
          const float4 v0 = s[0], v1 = s[1];
          v[0]=v0.x; v[1]=v0.y; v[2]=v0.z; v[3]=v0.w;
          v[4]=v1.x; v[5]=v1.y; v[6]=v1.z; v[7]=v1.w;
        } else {
#pragma unroll
          for (int e = 0; e < 8; ++e)
            if (k + e < EMBED) v[e] = W[(size_t)n * EMBED + k + e];
        }
      }
      short8 hv, lv;
#pragma unroll
      for (int e = 0; e < 8; ++e) { short hh, ll; split_hl(v[e], hh, ll); hv[e] = hh; lv[e] = ll; }
      const int off = (row << 6) + ((s8 ^ (row & 7)) << 3);
      *(short8*)&Bh[off] = hv;
      *(short8*)&Bl[off] = lv;
    }
    __syncthreads();
#pragma unroll
    for (int ks = 0; ks < 2; ++ks) {
      short8 a_h[4], a_l[4], b_h[4], b_l[4];
#pragma unroll
      for (int mr = 0; mr < 4; ++mr) {
        const int row = (wid << 6) + mr * 16 + lr;
        const int off = (row << 6) + (((ks * 4 + lg) ^ (row & 7)) << 3);
        a_h[mr] = *(const short8*)&Ah[off];
        a_l[mr] = *(const short8*)&Al[off];
      }
#pragma unroll
      for (int nr = 0; nr < 4; ++nr) {
        const int row = nr * 16 + lr;
        const int off = (row << 6) + (((ks * 4 + lg) ^ (row & 7)) << 3);
        b_h[nr] = *(const short8*)&Bh[off];
        b_l[nr] = *(const short8*)&Bl[off];
      }
#pragma unroll
      for (int mr = 0; mr < 4; ++mr)
#pragma unroll
        for (int nr = 0; nr < 4; ++nr) {
          acc[mr][nr] = __builtin_amdgcn_mfma_f32_16x16x32_bf16(a_h[mr], b_h[nr], acc[mr][nr], 0, 0, 0);
          acc[mr][nr] = __builtin_amdgcn_mfma_f32_16x16x32_bf16(a_h[mr], b_l[nr], acc[mr][nr], 0, 0, 0);
          acc[mr][nr] = __builtin_amdgcn_mfma_f32_16x16x32_bf16(a_l[mr], b_h[nr], acc[mr][nr], 0, 0, 0);
        }
    }
    __syncthreads();
  }
  // epilogue: D col = lane&15, row = (lane>>4)*4 + r
#pragma unroll
  for (int mr = 0; mr < 4; ++mr) {
    const int row0 = (wid << 6) + mr * 16 + lg * 4;
    if (row0 >= 200) continue;
#pragma unroll
    for (int nr = 0; nr < 4; ++nr) {
      const int col = n0 + nr * 16 + lr;
      if (col < EMBED) {
#pragma unroll
        for (int r = 0; r < 4; ++r)
          if (row0 + r < 200) Y[(size_t)(row0 + r) * EMBED + col] = acc[mr][nr][r];
      }
    }
  }
}

// ---------------------------------------------------------------------------
// Kernel 3b: Gt/At = sum over 4 kc partial planes. float4, 1055 blocks.
// ---------------------------------------------------------------------------
__global__ __launch_bounds__(256) void reduce_kernel(
    const float4* __restrict__ Yp, float4* __restrict__ Gt) {
  const int i = blockIdx.x * 256 + threadIdx.x;
  if (i < 270000) {
    const float4 a = Yp[i], b = Yp[i + 270000];
    const float4 c = Yp[i + 540000], d = Yp[i + 810000];
    Gt[i] = make_float4(a.x + b.x + c.x + d.x, a.y + b.y + c.y + d.y,
                        a.z + b.z + c.z + d.z, a.w + b.w + c.w + d.w);
  }
}

// ---------------------------------------------------------------------------
// Kernel 4a: sim partials. Block (kc, b2): simT for a 60-wide K chunk.
// ---------------------------------------------------------------------------
#define SKC 60
__global__ __launch_bounds__(256) void sim_gemm_kernel(
    const float* __restrict__ Gt, const float* __restrict__ At,
    float* __restrict__ part) {
  const int kc = blockIdx.x;   // 0..44
  const int b2 = blockIdx.y;   // 0..1
  __shared__ float Gs[112][SKC];
  __shared__ float As[112][SKC];
  const int tid = threadIdx.x;
  for (int e = tid; e < 100 * 15; e += 256) {
    const int r = e / 15, c = e % 15;
    const size_t src = (size_t)(b2 * 100 + r) * EMBED + kc * SKC + c * 4;
    *(float4*)&Gs[r][c * 4] = *(const float4*)&Gt[src];
    *(float4*)&As[r][c * 4] = *(const float4*)&At[src];
  }
  __syncthreads();
  const int tx = tid & 15, ty = tid >> 4;
  float acc[7][7] = {};
  for (int kd = 0; kd < SKC; kd += 4) {
    float4 g[7], a[7];
#pragma unroll
    for (int jq = 0; jq < 7; ++jq) g[jq] = *(const float4*)&Gs[tx + 16 * jq][kd];
#pragma unroll
    for (int ik = 0; ik < 7; ++ik) a[ik] = *(const float4*)&As[ty + 16 * ik][kd];
#pragma unroll
    for (int ik = 0; ik < 7; ++ik)
#pragma unroll
      for (int jq = 0; jq < 7; ++jq)
        acc[ik][jq] += a[ik].x * g[jq].x + a[ik].y * g[jq].y +
                       a[ik].z * g[jq].z + a[ik].w * g[jq].w;
  }
  float* pb = part + (size_t)(kc * 2 + b2) * 10000;
#pragma unroll
  for (int ik = 0; ik < 7; ++ik) {
    const int k = ty + 16 * ik;
    if (k < 100) {
#pragma unroll
      for (int jq = 0; jq < 7; ++jq) {
        const int q = tx + 16 * jq;
        if (q < 100) pb[k * 100 + q] = acc[ik][jq];
      }
    }
  }
}

// ---------------------------------------------------------------------------
// Kernel 4b: reduce over kc, softmax over q (dim 1), write out.
// ---------------------------------------------------------------------------
__global__ __launch_bounds__(256) void softmax_kernel(
    const float* __restrict__ part, float* __restrict__ out) {
  const int wid  = (blockIdx.x << 2) | (threadIdx.x >> 6);  // 0..199
  const int lane = threadIdx.x & 63;
  const int b2 = wid / 100, k = wid % 100;
  float s0 = 0.f, s1 = 0.f;
  for (int kc = 0; kc < 45; ++kc) {
    const float* p = part + ((size_t)(kc * 2 + b2) * 100 + k) * 100;
    s0 += p[lane];
    if (lane < 36) s1 += p[lane + 64];
  }
  const float scale = sqrtf(384.0f);
  const float v0 = s0 / scale;
  const float v1 = s1 / scale;
  float m = (lane < 36) ? fmaxf(v0, v1) : v0;
#pragma unroll
  for (int off = 32; off; off >>= 1) m = fmaxf(m, __shfl_down(m, off, 64));
  m = __shfl(m, 0, 64);
  const float e0 = expf(v0 - m);
  const float e1 = (lane < 36) ? expf(v1 - m) : 0.f;
  float d = e0 + e1;
#pragma unroll
  for (int off = 32; off; off >>= 1) d += __shfl_down(d, off, 64);
  d = __shfl(d, 0, 64);
  out[((size_t)b2 * 100 + lane) * 100 + k] = e0 / d;
  if (lane < 36) out[((size_t)b2 * 100 + lane + 64) * 100 + k] = e1 / d;
}

// ---------------------------------------------------------------------------
extern "C" void kernel_launch(void* const* d_in, const int* in_sizes, int n_in,
                              void* d_out, int out_size, void* d_ws, size_t ws_size,
                              hipStream_t stream) {
  const float* g_samples = (const float*)d_in[0];
  const float* a_samples = (const float*)d_in[1];
  const float* g_logits  = (const float*)d_in[2];
  const float* a_logits  = (const float*)d_in[3];
  const float* g_boxes   = (const float*)d_in[4];
  const float* a_boxes   = (const float*)d_in[5];
  const float* W_ground  = (const float*)d_in[6];
  const float* W_aerial  = (const float*)d_in[7];
  const float* pos_enc   = (const float*)d_in[8];
  float* out = (float*)d_out;
  float* ws  = (float*)d_ws;

  // ws layout (floats):
  float* boxes_px = ws;                          // 1600 (round to 2048)
  short* Xgh = (short*)(ws + 2048);              // 200*XSTR shorts = 270400 f
  short* Xgl = (short*)(ws + 2048 + 270400);
  short* Xah = (short*)(ws + 2048 + 540800);
  short* Xal = (short*)(ws + 2048 + 811200);
  float* Ypart = ws + 1083648;                   // 4 * YPLANE = 4,320,000 f
  float* Gt    = ws + 5403648;                   // 540,000 (Gt) + 540,000 (At)
  float* At    = Gt + 540000;
  float* part  = Ypart;                          // alias: Ypart dead after reduce

  topk_boxes_kernel<<<4, 256, 0, stream>>>(g_logits, a_logits, g_boxes, a_boxes, boxes_px);
  roi_kernel<<<1200, 256, 0, stream>>>(g_samples, a_samples, boxes_px, pos_enc,
                                       Xgh, Xgl, Xah, Xal);
  gemm_kernel<<<dim3(43, 4, 2), 256, 0, stream>>>(Xgh, Xgl, Xah, Xal,
                                                  W_ground, W_aerial, Ypart);
  reduce_kernel<<<1055, 256, 0, stream>>>((const float4*)Ypart, (float4*)Gt);
  sim_gemm_kernel<<<dim3(45, 2), 256, 0, stream>>>(Gt, At, part);
  softmax_kernel<<<50, 256, 0, stream>>>(part, out);
}

// Round 5
// 228.493 us; speedup vs baseline: 3.7035x; 1.0353x over previous
//
#include <hip/hip_runtime.h>
#include <math.h>

#define NTOPK 100
#define QC    6000
#define NC    20
#define EMBED 2700
#define IMGW  1024
#define XSTR  2704          // padded short stride for Xh/Xl rows
#define YPLANE 1080000      // 2*200*2700 floats per kc partial plane

typedef __attribute__((ext_vector_type(8))) short short8;
typedef __attribute__((ext_vector_type(4))) float f32x4;

__device__ inline short f32_bf16_rne(float x) {
  const unsigned u = __float_as_uint(x);
  return (short)((u + 0x7fffu + ((u >> 16) & 1u)) >> 16);
}
__device__ inline void split_hl(float x, short& h, short& l) {
  h = f32_bf16_rne(x);
  const float hf = __uint_as_float(((unsigned)(unsigned short)h) << 16);
  l = f32_bf16_rne(x - hf);
}
__device__ inline short8 zero8() {
  short8 z;
#pragma unroll
  for (int i = 0; i < 8; ++i) z[i] = 0;
  return z;
}

// ---------------------------------------------------------------------------
// Kernel 1: radix-select top-100 -> xyxy pixel boxes. grid 4, block 256.
// ---------------------------------------------------------------------------
__global__ __launch_bounds__(256) void topk_boxes_kernel(
    const float* __restrict__ g_logits, const float* __restrict__ a_logits,
    const float* __restrict__ g_boxes,  const float* __restrict__ a_boxes,
    float* __restrict__ boxes_px /* [2][2][100][4] */) {
  const int which = blockIdx.x >> 1;
  const int b     = blockIdx.x & 1;
  const float* logits = (which ? a_logits : g_logits) + b * QC;
  const float* boxes  = (which ? a_boxes  : g_boxes)  + b * 300 * 4;
  float* outb = boxes_px + (size_t)(which * 2 + b) * NTOPK * 4;

  __shared__ unsigned keys[QC];
  __shared__ int hist[4096];
  __shared__ int suf[257];
  __shared__ unsigned long long cand[256];
  __shared__ int s_cnt, s_bstar;

  const int tid = threadIdx.x;
  for (int i = tid; i < 4096; i += 256) hist[i] = 0;
  if (tid == 0) s_cnt = 0;
  __syncthreads();
  for (int j = tid; j < QC; j += 256) {
    const unsigned u = __float_as_uint(logits[j]);
    const unsigned k = u ^ ((u >> 31) ? 0xFFFFFFFFu : 0x80000000u);
    keys[j] = k;
    atomicAdd(&hist[k >> 20], 1);
  }
  __syncthreads();
  int cs = 0;
#pragma unroll
  for (int i = 0; i < 16; ++i) cs += hist[tid * 16 + i];
  suf[tid] = cs;
  if (tid == 0) suf[256] = 0;
  __syncthreads();
  for (int d = 1; d < 256; d <<= 1) {
    const int v = (tid + d < 256) ? suf[tid + d] : 0;
    __syncthreads();
    suf[tid] += v;
    __syncthreads();
  }
  if (suf[tid] >= NTOPK && (tid == 255 || suf[tid + 1] < NTOPK)) {
    int acc = suf[tid + 1];
    int bstar = tid * 16;
    for (int bb = tid * 16 + 15; bb >= tid * 16; --bb) {
      if (acc + hist[bb] >= NTOPK) { bstar = bb; break; }
      acc += hist[bb];
    }
    s_bstar = bstar;
  }
  __syncthreads();
  const unsigned bstar = (unsigned)s_bstar;
  for (int j = tid; j < QC; j += 256) {
    if ((keys[j] >> 20) >= bstar) {
      const int pos = atomicAdd(&s_cnt, 1);
      if (pos < 256)
        cand[pos] = (((unsigned long long)(~keys[j])) << 13) | (unsigned)j;
    }
  }
  __syncthreads();
  const int cnt = s_cnt < 256 ? s_cnt : 256;
  if (tid < cnt) {
    const unsigned long long me = cand[tid];
    int rank = 0;
    for (int j = 0; j < cnt; ++j) rank += (cand[j] < me);
    if (rank < NTOPK) {
      const int idx = (int)(me & 8191ULL);
      const int q = idx / NC;
      const float cx = boxes[q*4+0], cy = boxes[q*4+1];
      const float w  = boxes[q*4+2], h  = boxes[q*4+3];
      const float hw = __fmul_rn(0.5f, w), hh = __fmul_rn(0.5f, h);
      outb[rank*4+0] = __fmul_rn(__fsub_rn(cx, hw), 1024.0f);
      outb[rank*4+1] = __fmul_rn(__fsub_rn(cy, hh), 1024.0f);
      outb[rank*4+2] = __fmul_rn(__fadd_rn(cx, hw), 1024.0f);
      outb[rank*4+3] = __fmul_rn(__fadd_rn(cy, hh), 1024.0f);
    }
  }
}

// ---------------------------------------------------------------------------
// Kernel 2: bilinear ROI crops -> bf16 hi/lo X rows (+pos_enc), stride XSTR.
// grid 2400: (which, b*t, c, half). X row u = t*2 + b; pe row = u % 100.
// ---------------------------------------------------------------------------
__global__ __launch_bounds__(256) void roi_kernel(
    const float* __restrict__ g_samples, const float* __restrict__ a_samples,
    const float* __restrict__ boxes_px, const float* __restrict__ pos_enc,
    short* __restrict__ Xgh, short* __restrict__ Xgl,
    short* __restrict__ Xah, short* __restrict__ Xal) {
  const int bi = blockIdx.x;
  const int which = bi / 1200;
  const int rem = bi % 1200;
  const int p = rem / 6;
  const int sub = rem % 6;
  const int c = sub >> 1, half = sub & 1;
  const int b = p / 100, t = p % 100;
  const int u = t * 2 + b;
  const float* ic = (which ? a_samples : g_samples)
                    + ((size_t)b * 3 + c) * IMGW * IMGW;
  const float* bx = boxes_px + ((size_t)(which * 2 + b) * NTOPK + t) * 4;
  short* xh = (which ? Xah : Xgh) + (size_t)u * XSTR + c * 900;
  short* xl = (which ? Xal : Xgl) + (size_t)u * XSTR + c * 900;
  const float* pe = pos_enc + (size_t)(u % 100) * EMBED + c * 900;

  __shared__ float s_wy[30], s_wx[30];
  __shared__ int   s_y0i[30], s_y1i[30], s_x0i[30], s_x1i[30];
  __shared__ float s_valid;

  const float x0 = rintf(bx[0]), y0 = rintf(bx[1]);
  const float x1 = rintf(bx[2]), y1 = rintf(bx[3]);
  const float w = __fsub_rn(x1, x0), h = __fsub_rn(y1, y0);
  const int tid = threadIdx.x;
  if (tid == 0) s_valid = (w > 0.0f && h > 0.0f) ? 1.0f : 0.0f;
  if (tid < 30) {
    const float g  = (float)tid + 0.5f;
    float sy = __fsub_rn(__fdiv_rn(__fmul_rn(g, h), 30.0f), 0.5f);
    const float hm1 = fmaxf(__fsub_rn(h, 1.0f), 0.0f);
    sy = fminf(fmaxf(sy, 0.0f), hm1);
    const float ay = __fadd_rn(y0, sy);
    const float yf = floorf(ay);
    s_wy[tid]  = __fsub_rn(ay, yf);
    s_y0i[tid] = (int)fminf(fmaxf(yf, 0.0f), 1023.0f);
    s_y1i[tid] = (int)fminf(fmaxf(yf + 1.0f, 0.0f), 1023.0f);
  } else if (tid >= 32 && tid < 62) {
    const int i = tid - 32;
    const float g = (float)i + 0.5f;
    float sx = __fsub_rn(__fdiv_rn(__fmul_rn(g, w), 30.0f), 0.5f);
    const float wm1 = fmaxf(__fsub_rn(w, 1.0f), 0.0f);
    sx = fminf(fmaxf(sx, 0.0f), wm1);
    const float ax = __fadd_rn(x0, sx);
    const float xf = floorf(ax);
    s_wx[i]  = __fsub_rn(ax, xf);
    s_x0i[i] = (int)fminf(fmaxf(xf, 0.0f), 1023.0f);
    s_x1i[i] = (int)fminf(fmaxf(xf + 1.0f, 0.0f), 1023.0f);
  }
  __syncthreads();
  const float valid = s_valid;
  const int pbeg = half * 450, pend = pbeg + 450;
  for (int pix = pbeg + tid; pix < pend; pix += 256) {
    const int py = pix / 30, px = pix % 30;
    const int yi0 = s_y0i[py], yi1 = s_y1i[py], xi0 = s_x0i[px], xi1 = s_x1i[px];
    const float wy = s_wy[py], wx = s_wx[px];
    const float p00 = ic[yi0 * IMGW + xi0], p01 = ic[yi0 * IMGW + xi1];
    const float p10 = ic[yi1 * IMGW + xi0], p11 = ic[yi1 * IMGW + xi1];
    const float top = p00 * (1.0f - wx) + p01 * wx;
    const float bot = p10 * (1.0f - wx) + p11 * wx;
    const float val = top * (1.0f - wy) + bot * wy;
    const float x = val * valid + pe[pix];
    short hb, lb;
    split_hl(x, hb, lb);
    xh[pix] = hb;
    xl[pix] = lb;
  }
  // zero the 4 pad shorts of each row once
  if (c == 2 && half == 1 && tid < 4) {
    short* bh = (which ? Xah : Xgh) + (size_t)u * XSTR;
    short* bl = (which ? Xal : Xgl) + (size_t)u * XSTR;
    bh[2700 + tid] = 0;
    bl[2700 + tid] = 0;
  }
}

// ---------------------------------------------------------------------------
// Kernel 3: Ypart[kc] = X @ W^T (K chunk kc), bf16 hi/lo MFMA.
// A-fragments loaded DIRECTLY from global (X is bf16, L2-resident) — no A LDS.
// Only W staged through LDS (16 KB). grid (43, 4 kc, 2 which), 4 waves.
// Wave w owns m-tiles {w, w+4, w+8, w+12}; block owns n0..n0+63.
// ---------------------------------------------------------------------------
__global__ __launch_bounds__(256) void gemm_kernel(
    const short* __restrict__ Xgh, const short* __restrict__ Xgl,
    const short* __restrict__ Xah, const short* __restrict__ Xal,
    const float* __restrict__ Wg, const float* __restrict__ Wa,
    float* __restrict__ Ypart) {
  const int which = blockIdx.z;
  const int kc    = blockIdx.y;
  const short* Xh = which ? Xah : Xgh;
  const short* Xl = which ? Xal : Xgl;
  const float* W  = which ? Wa  : Wg;
  float* Y = Ypart + (size_t)kc * YPLANE + (size_t)which * 540000;
  const int n0 = blockIdx.x * 64;
  const int kbeg = kc * 704;
  const int ksteps = (kc < 3) ? 11 : 10;

  __shared__ short Bh[64 * 64], Bl[64 * 64];

  const int tid = threadIdx.x;
  const int lane = tid & 63, wid = tid >> 6;
  const int lr = lane & 15, lg = lane >> 4;

  f32x4 acc[4][4] = {};

  for (int t = 0; t < ksteps; ++t) {
    const int k0 = kbeg + t * 64;
    // ---- stage B: 64 rows x 8 chunks, f32 -> hi/lo convert ----
#pragma unroll
    for (int it = 0; it < 2; ++it) {
      const int cid = it * 256 + tid;
      const int row = cid >> 3, s8 = cid & 7;
      const int n = n0 + row;
      const int k = k0 + s8 * 8;
      float v[8];
#pragma unroll
      for (int e = 0; e < 8; ++e) v[e] = 0.0f;
      if (n < EMBED) {
        if (k + 8 <= EMBED) {
          const float4* s = (const float4*)&W[(size_t)n * EMBED + k];
          const float4 v0 = s[0], v1 = s[1];
          v[0]=v0.x; v[1]=v0.y; v[2]=v0.z; v[3]=v0.w;
          v[4]=v1.x; v[5]=v1.y; v[6]=v1.z; v[7]=v1.w;
        } else {
#pragma unroll
          for (int e = 0; e < 8; ++e)
            if (k + e < EMBED) v[e] = W[(size_t)n * EMBED + k + e];
        }
      }
      short8 hv, lv;
#pragma unroll
      for (int e = 0; e < 8; ++e) { short hh, ll; split_hl(v[e], hh, ll); hv[e] = hh; lv[e] = ll; }
      const int off = (row << 6) + ((s8 ^ (row & 7)) << 3);
      *(short8*)&Bh[off] = hv;
      *(short8*)&Bl[off] = lv;
    }
    __syncthreads();
#pragma unroll
    for (int ks = 0; ks < 2; ++ks) {
      const int kst = k0 + ks * 32 + lg * 8;
      short8 ah[4], al[4], bh[4], bl[4];
#pragma unroll
      for (int nt = 0; nt < 4; ++nt) {
        const int brow = nt * 16 + lr;
        const int boff = (brow << 6) + (((ks * 4 + lg) ^ (brow & 7)) << 3);
        bh[nt] = *(const short8*)&Bh[boff];
        bl[nt] = *(const short8*)&Bl[boff];
      }
#pragma unroll
      for (int j = 0; j < 4; ++j) {
        const int row = (wid + 4 * j) * 16 + lr;
        ah[j] = zero8();
        al[j] = zero8();
        if (row < 200 && kst < EMBED) {
          const size_t off = (size_t)row * XSTR + kst;
          ah[j] = *(const short8*)&Xh[off];
          al[j] = *(const short8*)&Xl[off];
        }
      }
#pragma unroll
      for (int j = 0; j < 4; ++j)
#pragma unroll
        for (int nt = 0; nt < 4; ++nt) {
          acc[j][nt] = __builtin_amdgcn_mfma_f32_16x16x32_bf16(ah[j], bh[nt], acc[j][nt], 0, 0, 0);
          acc[j][nt] = __builtin_amdgcn_mfma_f32_16x16x32_bf16(ah[j], bl[nt], acc[j][nt], 0, 0, 0);
          acc[j][nt] = __builtin_amdgcn_mfma_f32_16x16x32_bf16(al[j], bh[nt], acc[j][nt], 0, 0, 0);
        }
    }
    __syncthreads();
  }
  // epilogue: D col = lane&15, row = (lane>>4)*4 + r
#pragma unroll
  for (int j = 0; j < 4; ++j) {
    const int row0 = (wid + 4 * j) * 16 + lg * 4;
    if (row0 >= 200) continue;
#pragma unroll
    for (int nt = 0; nt < 4; ++nt) {
      const int col = n0 + nt * 16 + lr;
      if (col < EMBED) {
#pragma unroll
        for (int r = 0; r < 4; ++r)
          if (row0 + r < 200) Y[(size_t)(row0 + r) * EMBED + col] = acc[j][nt][r];
      }
    }
  }
}

// ---------------------------------------------------------------------------
// Kernel 4a: sim partials with fused 4-plane reduction of Ypart.
// Block (kc2, b2): simT for a 60-wide K chunk; Gs/As = sum of 4 planes.
// ---------------------------------------------------------------------------
#define SKC 60
__global__ __launch_bounds__(256) void sim_gemm_kernel(
    const float* __restrict__ Ypart, float* __restrict__ part) {
  const int kc2 = blockIdx.x;  // 0..44
  const int b2  = blockIdx.y;  // 0..1
  __shared__ float Gs[112][SKC];
  __shared__ float As[112][SKC];
  const int tid = threadIdx.x;
  for (int e = tid; e < 100 * 15; e += 256) {
    const int r = e / 15, c = e % 15;
    const size_t base = (size_t)(b2 * 100 + r) * EMBED + kc2 * SKC + c * 4;
    float4 g = make_float4(0.f, 0.f, 0.f, 0.f);
    float4 a = make_float4(0.f, 0.f, 0.f, 0.f);
#pragma unroll
    for (int pl = 0; pl < 4; ++pl) {
      const float4 gv = *(const float4*)&Ypart[(size_t)pl * YPLANE + base];
      const float4 av = *(const float4*)&Ypart[(size_t)pl * YPLANE + 540000 + base];
      g.x += gv.x; g.y += gv.y; g.z += gv.z; g.w += gv.w;
      a.x += av.x; a.y += av.y; a.z += av.z; a.w += av.w;
    }
    *(float4*)&Gs[r][c * 4] = g;
    *(float4*)&As[r][c * 4] = a;
  }
  __syncthreads();
  const int tx = tid & 15, ty = tid >> 4;
  float acc[7][7] = {};
  for (int kd = 0; kd < SKC; kd += 4) {
    float4 g[7], a[7];
#pragma unroll
    for (int jq = 0; jq < 7; ++jq) g[jq] = *(const float4*)&Gs[tx + 16 * jq][kd];
#pragma unroll
    for (int ik = 0; ik < 7; ++ik) a[ik] = *(const float4*)&As[ty + 16 * ik][kd];
#pragma unroll
    for (int ik = 0; ik < 7; ++ik)
#pragma unroll
      for (int jq = 0; jq < 7; ++jq)
        acc[ik][jq] += a[ik].x * g[jq].x + a[ik].y * g[jq].y +
                       a[ik].z * g[jq].z + a[ik].w * g[jq].w;
  }
  float* pb = part + (size_t)(kc2 * 2 + b2) * 10000;
#pragma unroll
  for (int ik = 0; ik < 7; ++ik) {
    const int k = ty + 16 * ik;
    if (k < 100) {
#pragma unroll
      for (int jq = 0; jq < 7; ++jq) {
        const int q = tx + 16 * jq;
        if (q < 100) pb[k * 100 + q] = acc[ik][jq];
      }
    }
  }
}

// ---------------------------------------------------------------------------
// Kernel 4b: reduce over kc2, softmax over q (dim 1), write out.
// ---------------------------------------------------------------------------
__global__ __launch_bounds__(256) void softmax_kernel(
    const float* __restrict__ part, float* __restrict__ out) {
  const int wid  = (blockIdx.x << 2) | (threadIdx.x >> 6);  // 0..199
  const int lane = threadIdx.x & 63;
  const int b2 = wid / 100, k = wid % 100;
  float s0 = 0.f, s1 = 0.f;
  for (int kc = 0; kc < 45; ++kc) {
    const float* p = part + ((size_t)(kc * 2 + b2) * 100 + k) * 100;
    s0 += p[lane];
    if (lane < 36) s1 += p[lane + 64];
  }
  const float scale = sqrtf(384.0f);
  const float v0 = s0 / scale;
  const float v1 = s1 / scale;
  float m = (lane < 36) ? fmaxf(v0, v1) : v0;
#pragma unroll
  for (int off = 32; off; off >>= 1) m = fmaxf(m, __shfl_down(m, off, 64));
  m = __shfl(m, 0, 64);
  const float e0 = expf(v0 - m);
  const float e1 = (lane < 36) ? expf(v1 - m) : 0.f;
  float d = e0 + e1;
#pragma unroll
  for (int off = 32; off; off >>= 1) d += __shfl_down(d, off, 64);
  d = __shfl(d, 0, 64);
  out[((size_t)b2 * 100 + lane) * 100 + k] = e0 / d;
  if (lane < 36) out[((size_t)b2 * 100 + lane + 64) * 100 + k] = e1 / d;
}

// ---------------------------------------------------------------------------
extern "C" void kernel_launch(void* const* d_in, const int* in_sizes, int n_in,
                              void* d_out, int out_size, void* d_ws, size_t ws_size,
                              hipStream_t stream) {
  const float* g_samples = (const float*)d_in[0];
  const float* a_samples = (const float*)d_in[1];
  const float* g_logits  = (const float*)d_in[2];
  const float* a_logits  = (const float*)d_in[3];
  const float* g_boxes   = (const float*)d_in[4];
  const float* a_boxes   = (const float*)d_in[5];
  const float* W_ground  = (const float*)d_in[6];
  const float* W_aerial  = (const float*)d_in[7];
  const float* pos_enc   = (const float*)d_in[8];
  float* out = (float*)d_out;
  float* ws  = (float*)d_ws;

  // ws layout (floats):
  float* boxes_px = ws;                          // 1600 (round to 2048)
  short* Xgh = (short*)(ws + 2048);              // 200*XSTR shorts = 270400 f
  short* Xgl = (short*)(ws + 2048 + 270400);
  short* Xah = (short*)(ws + 2048 + 540800);
  short* Xal = (short*)(ws + 2048 + 811200);
  float* Ypart = ws + 1083648;                   // 4 * YPLANE = 4,320,000 f
  float* part  = ws + 5403648;                   // 900,000 f

  topk_boxes_kernel<<<4, 256, 0, stream>>>(g_logits, a_logits, g_boxes, a_boxes, boxes_px);
  roi_kernel<<<2400, 256, 0, stream>>>(g_samples, a_samples, boxes_px, pos_enc,
                                       Xgh, Xgl, Xah, Xal);
  gemm_kernel<<<dim3(43, 4, 2), 256, 0, stream>>>(Xgh, Xgl, Xah, Xal,
                                                  W_ground, W_aerial, Ypart);
  sim_gemm_kernel<<<dim3(45, 2), 256, 0, stream>>>(Ypart, part);
  softmax_kernel<<<50, 256, 0, stream>>>(part, out);
}

// Round 6
// 227.157 us; speedup vs baseline: 3.7253x; 1.0059x over previous
//
#include <hip/hip_runtime.h>
#include <math.h>

#define NTOPK 100
#define QC    6000
#define NC    20
#define EMBED 2700
#define IMGW  1024
#define XSTR  2704          // padded short stride for Xh/Xl rows
#define YPLANE 1080000      // 2*200*2700 floats per kc partial plane
#define NKC   8             // gemm K-split chunks
#define NSIMKC 75           // sim K chunks (SKC=36)

typedef __attribute__((ext_vector_type(8))) short short8;
typedef __attribute__((ext_vector_type(4))) float f32x4;

__device__ inline short f32_bf16_rne(float x) {
  const unsigned u = __float_as_uint(x);
  return (short)((u + 0x7fffu + ((u >> 16) & 1u)) >> 16);
}
__device__ inline void split_hl(float x, short& h, short& l) {
  h = f32_bf16_rne(x);
  const float hf = __uint_as_float(((unsigned)(unsigned short)h) << 16);
  l = f32_bf16_rne(x - hf);
}
__device__ inline short8 zero8() {
  short8 z;
#pragma unroll
  for (int i = 0; i < 8; ++i) z[i] = 0;
  return z;
}

// ---------------------------------------------------------------------------
// Kernel 1: radix-select top-100 -> xyxy pixel boxes. grid 4, block 256.
// ---------------------------------------------------------------------------
__global__ __launch_bounds__(256) void topk_boxes_kernel(
    const float* __restrict__ g_logits, const float* __restrict__ a_logits,
    const float* __restrict__ g_boxes,  const float* __restrict__ a_boxes,
    float* __restrict__ boxes_px /* [2][2][100][4] */) {
  const int which = blockIdx.x >> 1;
  const int b     = blockIdx.x & 1;
  const float* logits = (which ? a_logits : g_logits) + b * QC;
  const float* boxes  = (which ? a_boxes  : g_boxes)  + b * 300 * 4;
  float* outb = boxes_px + (size_t)(which * 2 + b) * NTOPK * 4;

  __shared__ unsigned keys[QC];
  __shared__ int hist[4096];
  __shared__ int suf[257];
  __shared__ unsigned long long cand[256];
  __shared__ int s_cnt, s_bstar;

  const int tid = threadIdx.x;
  for (int i = tid; i < 4096; i += 256) hist[i] = 0;
  if (tid == 0) s_cnt = 0;
  __syncthreads();
  for (int j = tid; j < QC; j += 256) {
    const unsigned u = __float_as_uint(logits[j]);
    const unsigned k = u ^ ((u >> 31) ? 0xFFFFFFFFu : 0x80000000u);
    keys[j] = k;
    atomicAdd(&hist[k >> 20], 1);
  }
  __syncthreads();
  int cs = 0;
#pragma unroll
  for (int i = 0; i < 16; ++i) cs += hist[tid * 16 + i];
  suf[tid] = cs;
  if (tid == 0) suf[256] = 0;
  __syncthreads();
  for (int d = 1; d < 256; d <<= 1) {
    const int v = (tid + d < 256) ? suf[tid + d] : 0;
    __syncthreads();
    suf[tid] += v;
    __syncthreads();
  }
  if (suf[tid] >= NTOPK && (tid == 255 || suf[tid + 1] < NTOPK)) {
    int acc = suf[tid + 1];
    int bstar = tid * 16;
    for (int bb = tid * 16 + 15; bb >= tid * 16; --bb) {
      if (acc + hist[bb] >= NTOPK) { bstar = bb; break; }
      acc += hist[bb];
    }
    s_bstar = bstar;
  }
  __syncthreads();
  const unsigned bstar = (unsigned)s_bstar;
  for (int j = tid; j < QC; j += 256) {
    if ((keys[j] >> 20) >= bstar) {
      const int pos = atomicAdd(&s_cnt, 1);
      if (pos < 256)
        cand[pos] = (((unsigned long long)(~keys[j])) << 13) | (unsigned)j;
    }
  }
  __syncthreads();
  const int cnt = s_cnt < 256 ? s_cnt : 256;
  if (tid < cnt) {
    const unsigned long long me = cand[tid];
    int rank = 0;
    for (int j = 0; j < cnt; ++j) rank += (cand[j] < me);
    if (rank < NTOPK) {
      const int idx = (int)(me & 8191ULL);
      const int q = idx / NC;
      const float cx = boxes[q*4+0], cy = boxes[q*4+1];
      const float w  = boxes[q*4+2], h  = boxes[q*4+3];
      const float hw = __fmul_rn(0.5f, w), hh = __fmul_rn(0.5f, h);
      outb[rank*4+0] = __fmul_rn(__fsub_rn(cx, hw), 1024.0f);
      outb[rank*4+1] = __fmul_rn(__fsub_rn(cy, hh), 1024.0f);
      outb[rank*4+2] = __fmul_rn(__fadd_rn(cx, hw), 1024.0f);
      outb[rank*4+3] = __fmul_rn(__fadd_rn(cy, hh), 1024.0f);
    }
  }
}

// ---------------------------------------------------------------------------
// Kernel 2: bilinear ROI crops -> bf16 hi/lo X rows (+pos_enc), stride XSTR.
// grid 2400: (which, b*t, c, half). X row u = t*2 + b; pe row = u % 100.
// ---------------------------------------------------------------------------
__global__ __launch_bounds__(256) void roi_kernel(
    const float* __restrict__ g_samples, const float* __restrict__ a_samples,
    const float* __restrict__ boxes_px, const float* __restrict__ pos_enc,
    short* __restrict__ Xgh, short* __restrict__ Xgl,
    short* __restrict__ Xah, short* __restrict__ Xal) {
  const int bi = blockIdx.x;
  const int which = bi / 1200;
  const int rem = bi % 1200;
  const int p = rem / 6;
  const int sub = rem % 6;
  const int c = sub >> 1, half = sub & 1;
  const int b = p / 100, t = p % 100;
  const int u = t * 2 + b;
  const float* ic = (which ? a_samples : g_samples)
                    + ((size_t)b * 3 + c) * IMGW * IMGW;
  const float* bx = boxes_px + ((size_t)(which * 2 + b) * NTOPK + t) * 4;
  short* xh = (which ? Xah : Xgh) + (size_t)u * XSTR + c * 900;
  short* xl = (which ? Xal : Xgl) + (size_t)u * XSTR + c * 900;
  const float* pe = pos_enc + (size_t)(u % 100) * EMBED + c * 900;

  __shared__ float s_wy[30], s_wx[30];
  __shared__ int   s_y0i[30], s_y1i[30], s_x0i[30], s_x1i[30];
  __shared__ float s_valid;

  const float x0 = rintf(bx[0]), y0 = rintf(bx[1]);
  const float x1 = rintf(bx[2]), y1 = rintf(bx[3]);
  const float w = __fsub_rn(x1, x0), h = __fsub_rn(y1, y0);
  const int tid = threadIdx.x;
  if (tid == 0) s_valid = (w > 0.0f && h > 0.0f) ? 1.0f : 0.0f;
  if (tid < 30) {
    const float g  = (float)tid + 0.5f;
    float sy = __fsub_rn(__fdiv_rn(__fmul_rn(g, h), 30.0f), 0.5f);
    const float hm1 = fmaxf(__fsub_rn(h, 1.0f), 0.0f);
    sy = fminf(fmaxf(sy, 0.0f), hm1);
    const float ay = __fadd_rn(y0, sy);
    const float yf = floorf(ay);
    s_wy[tid]  = __fsub_rn(ay, yf);
    s_y0i[tid] = (int)fminf(fmaxf(yf, 0.0f), 1023.0f);
    s_y1i[tid] = (int)fminf(fmaxf(yf + 1.0f, 0.0f), 1023.0f);
  } else if (tid >= 32 && tid < 62) {
    const int i = tid - 32;
    const float g = (float)i + 0.5f;
    float sx = __fsub_rn(__fdiv_rn(__fmul_rn(g, w), 30.0f), 0.5f);
    const float wm1 = fmaxf(__fsub_rn(w, 1.0f), 0.0f);
    sx = fminf(fmaxf(sx, 0.0f), wm1);
    const float ax = __fadd_rn(x0, sx);
    const float xf = floorf(ax);
    s_wx[i]  = __fsub_rn(ax, xf);
    s_x0i[i] = (int)fminf(fmaxf(xf, 0.0f), 1023.0f);
    s_x1i[i] = (int)fminf(fmaxf(xf + 1.0f, 0.0f), 1023.0f);
  }
  __syncthreads();
  const float valid = s_valid;
  const int pbeg = half * 450, pend = pbeg + 450;
  for (int pix = pbeg + tid; pix < pend; pix += 256) {
    const int py = pix / 30, px = pix % 30;
    const int yi0 = s_y0i[py], yi1 = s_y1i[py], xi0 = s_x0i[px], xi1 = s_x1i[px];
    const float wy = s_wy[py], wx = s_wx[px];
    const float p00 = ic[yi0 * IMGW + xi0], p01 = ic[yi0 * IMGW + xi1];
    const float p10 = ic[yi1 * IMGW + xi0], p11 = ic[yi1 * IMGW + xi1];
    const float top = p00 * (1.0f - wx) + p01 * wx;
    const float bot = p10 * (1.0f - wx) + p11 * wx;
    const float val = top * (1.0f - wy) + bot * wy;
    const float x = val * valid + pe[pix];
    short hb, lb;
    split_hl(x, hb, lb);
    xh[pix] = hb;
    xl[pix] = lb;
  }
  if (c == 2 && half == 1 && tid < 4) {
    short* bh = (which ? Xah : Xgh) + (size_t)u * XSTR;
    short* bl = (which ? Xal : Xgl) + (size_t)u * XSTR;
    bh[2700 + tid] = 0;
    bl[2700 + tid] = 0;
  }
}

// ---------------------------------------------------------------------------
// Kernel 3: Ypart[kc] = X @ W^T (K steps [43kc/8, 43(kc+1)/8)), hi/lo MFMA.
// A direct global->VGPR; W staged via 16 KB LDS. grid (43, 8, 2), 4 waves.
// ---------------------------------------------------------------------------
__global__ __launch_bounds__(256) void gemm_kernel(
    const short* __restrict__ Xgh, const short* __restrict__ Xgl,
    const short* __restrict__ Xah, const short* __restrict__ Xal,
    const float* __restrict__ Wg, const float* __restrict__ Wa,
    float* __restrict__ Ypart) {
  const int which = blockIdx.z;
  const int kc    = blockIdx.y;
  const short* Xh = which ? Xah : Xgh;
  const short* Xl = which ? Xal : Xgl;
  const float* W  = which ? Wa  : Wg;
  float* Y = Ypart + (size_t)kc * YPLANE + (size_t)which * 540000;
  const int n0 = blockIdx.x * 64;
  const int sb = (kc * 43) >> 3;
  const int se = ((kc + 1) * 43) >> 3;

  __shared__ short Bh[64 * 64], Bl[64 * 64];

  const int tid = threadIdx.x;
  const int lane = tid & 63, wid = tid >> 6;
  const int lr = lane & 15, lg = lane >> 4;

  f32x4 acc[4][4] = {};

  for (int t = sb; t < se; ++t) {
    const int k0 = t * 64;
    // ---- stage B: 64 rows x 8 chunks, f32 -> hi/lo convert ----
#pragma unroll
    for (int it = 0; it < 2; ++it) {
      const int cid = it * 256 + tid;
      const int row = cid >> 3, s8 = cid & 7;
      const int n = n0 + row;
      const int k = k0 + s8 * 8;
      float v[8];
#pragma unroll
      for (int e = 0; e < 8; ++e) v[e] = 0.0f;
      if (n < EMBED) {
        if (k + 8 <= EMBED) {
          const float4* s = (const float4*)&W[(size_t)n * EMBED + k];
          const float4 v0 = s[0], v1 = s[1];
          v[0]=v0.x; v[1]=v0.y; v[2]=v0.z; v[3]=v0.w;
          v[4]=v1.x; v[5]=v1.y; v[6]=v1.z; v[7]=v1.w;
        } else {
#pragma unroll
          for (int e = 0; e < 8; ++e)
            if (k + e < EMBED) v[e] = W[(size_t)n * EMBED + k + e];
        }
      }
      short8 hv, lv;
#pragma unroll
      for (int e = 0; e < 8; ++e) { short hh, ll; split_hl(v[e], hh, ll); hv[e] = hh; lv[e] = ll; }
      const int off = (row << 6) + ((s8 ^ (row & 7)) << 3);
      *(short8*)&Bh[off] = hv;
      *(short8*)&Bl[off] = lv;
    }
    __syncthreads();
#pragma unroll
    for (int ks = 0; ks < 2; ++ks) {
      const int kst = k0 + ks * 32 + lg * 8;
      short8 ah[4], al[4], bh[4], bl[4];
#pragma unroll
      for (int nt = 0; nt < 4; ++nt) {
        const int brow = nt * 16 + lr;
        const int boff = (brow << 6) + (((ks * 4 + lg) ^ (brow & 7)) << 3);
        bh[nt] = *(const short8*)&Bh[boff];
        bl[nt] = *(const short8*)&Bl[boff];
      }
#pragma unroll
      for (int j = 0; j < 4; ++j) {
        const int row = (wid + 4 * j) * 16 + lr;
        ah[j] = zero8();
        al[j] = zero8();
        if (row < 200 && kst < EMBED) {
          const size_t off = (size_t)row * XSTR + kst;
          ah[j] = *(const short8*)&Xh[off];
          al[j] = *(const short8*)&Xl[off];
        }
      }
#pragma unroll
      for (int j = 0; j < 4; ++j)
#pragma unroll
        for (int nt = 0; nt < 4; ++nt) {
          acc[j][nt] = __builtin_amdgcn_mfma_f32_16x16x32_bf16(ah[j], bh[nt], acc[j][nt], 0, 0, 0);
          acc[j][nt] = __builtin_amdgcn_mfma_f32_16x16x32_bf16(ah[j], bl[nt], acc[j][nt], 0, 0, 0);
          acc[j][nt] = __builtin_amdgcn_mfma_f32_16x16x32_bf16(al[j], bh[nt], acc[j][nt], 0, 0, 0);
        }
    }
    __syncthreads();
  }
  // epilogue: D col = lane&15, row = (lane>>4)*4 + r
#pragma unroll
  for (int j = 0; j < 4; ++j) {
    const int row0 = (wid + 4 * j) * 16 + lg * 4;
    if (row0 >= 200) continue;
#pragma unroll
    for (int nt = 0; nt < 4; ++nt) {
      const int col = n0 + nt * 16 + lr;
      if (col < EMBED) {
#pragma unroll
        for (int r = 0; r < 4; ++r)
          if (row0 + r < 200) Y[(size_t)(row0 + r) * EMBED + col] = acc[j][nt][r];
      }
    }
  }
}

// ---------------------------------------------------------------------------
// Kernel 4a: sim partials, fused 8-plane reduce. Block (kc2, b2), SKC=36.
// grid (75, 2). part plane = kc2*2 + b2.
// ---------------------------------------------------------------------------
#define SKC 36
__global__ __launch_bounds__(256) void sim_gemm_kernel(
    const float* __restrict__ Ypart, float* __restrict__ part) {
  const int kc2 = blockIdx.x;  // 0..74
  const int b2  = blockIdx.y;  // 0..1
  __shared__ float Gs[112][SKC];
  __shared__ float As[112][SKC];
  const int tid = threadIdx.x;
  for (int e = tid; e < 100 * 9; e += 256) {
    const int r = e / 9, c = e % 9;
    const size_t base = (size_t)(b2 * 100 + r) * EMBED + kc2 * SKC + c * 4;
    float4 g = make_float4(0.f, 0.f, 0.f, 0.f);
    float4 a = make_float4(0.f, 0.f, 0.f, 0.f);
#pragma unroll
    for (int pl = 0; pl < NKC; ++pl) {
      const float4 gv = *(const float4*)&Ypart[(size_t)pl * YPLANE + base];
      const float4 av = *(const float4*)&Ypart[(size_t)pl * YPLANE + 540000 + base];
      g.x += gv.x; g.y += gv.y; g.z += gv.z; g.w += gv.w;
      a.x += av.x; a.y += av.y; a.z += av.z; a.w += av.w;
    }
    *(float4*)&Gs[r][c * 4] = g;
    *(float4*)&As[r][c * 4] = a;
  }
  __syncthreads();
  const int tx = tid & 15, ty = tid >> 4;
  float acc[7][7] = {};
  for (int kd = 0; kd < SKC; kd += 4) {
    float4 g[7], a[7];
#pragma unroll
    for (int jq = 0; jq < 7; ++jq) g[jq] = *(const float4*)&Gs[tx + 16 * jq][kd];
#pragma unroll
    for (int ik = 0; ik < 7; ++ik) a[ik] = *(const float4*)&As[ty + 16 * ik][kd];
#pragma unroll
    for (int ik = 0; ik < 7; ++ik)
#pragma unroll
      for (int jq = 0; jq < 7; ++jq)
        acc[ik][jq] += a[ik].x * g[jq].x + a[ik].y * g[jq].y +
                       a[ik].z * g[jq].z + a[ik].w * g[jq].w;
  }
  float* pb = part + (size_t)(kc2 * 2 + b2) * 10000;
#pragma unroll
  for (int ik = 0; ik < 7; ++ik) {
    const int k = ty + 16 * ik;
    if (k < 100) {
#pragma unroll
      for (int jq = 0; jq < 7; ++jq) {
        const int q = tx + 16 * jq;
        if (q < 100) pb[k * 100 + q] = acc[ik][jq];
      }
    }
  }
}

// ---------------------------------------------------------------------------
// Kernel 4b: reduce over 75 planes, softmax over q (dim 1), write out.
// grid 200 (one column each), block 128 (2 waves; threads 0..99 = q).
// ---------------------------------------------------------------------------
__global__ __launch_bounds__(128) void softmax_kernel(
    const float* __restrict__ part, float* __restrict__ out) {
  const int col = blockIdx.x;          // 0..199
  const int b2 = col / 100, k = col % 100;
  const int tid = threadIdx.x;
  __shared__ float red[2];
  float v = -1e30f;
  if (tid < 100) {
    float acc = 0.f;
    for (int kc = 0; kc < NSIMKC; ++kc)
      acc += part[(size_t)(kc * 2 + b2) * 10000 + k * 100 + tid];
    v = acc / sqrtf(384.0f);
  }
  // max over 128 threads (idle lanes hold -1e30)
  float m = v;
#pragma unroll
  for (int off = 32; off; off >>= 1) m = fmaxf(m, __shfl_down(m, off, 64));
  if ((tid & 63) == 0) red[tid >> 6] = m;
  __syncthreads();
  m = fmaxf(red[0], red[1]);
  const float e = (tid < 100) ? expf(v - m) : 0.f;
  float d = e;
#pragma unroll
  for (int off = 32; off; off >>= 1) d += __shfl_down(d, off, 64);
  __syncthreads();
  if ((tid & 63) == 0) red[tid >> 6] = d;
  __syncthreads();
  d = red[0] + red[1];
  if (tid < 100) out[((size_t)b2 * 100 + tid) * 100 + k] = e / d;
}

// ---------------------------------------------------------------------------
extern "C" void kernel_launch(void* const* d_in, const int* in_sizes, int n_in,
                              void* d_out, int out_size, void* d_ws, size_t ws_size,
                              hipStream_t stream) {
  const float* g_samples = (const float*)d_in[0];
  const float* a_samples = (const float*)d_in[1];
  const float* g_logits  = (const float*)d_in[2];
  const float* a_logits  = (const float*)d_in[3];
  const float* g_boxes   = (const float*)d_in[4];
  const float* a_boxes   = (const float*)d_in[5];
  const float* W_ground  = (const float*)d_in[6];
  const float* W_aerial  = (const float*)d_in[7];
  const float* pos_enc   = (const float*)d_in[8];
  float* out = (float*)d_out;
  float* ws  = (float*)d_ws;

  // ws layout (floats):
  float* boxes_px = ws;                          // 1600 (reserve 2048)
  short* Xgh = (short*)(ws + 2048);              // each X array: 270,400 floats
  short* Xgl = (short*)(ws + 2048 + 270400);
  short* Xah = (short*)(ws + 2048 + 540800);
  short* Xal = (short*)(ws + 2048 + 811200);
  float* Ypart = ws + 1083648;                   // 8 * YPLANE = 8,640,000 f
  float* part  = ws + 9723648;                   // 150 * 10,000 = 1,500,000 f

  topk_boxes_kernel<<<4, 256, 0, stream>>>(g_logits, a_logits, g_boxes, a_boxes, boxes_px);
  roi_kernel<<<2400, 256, 0, stream>>>(g_samples, a_samples, boxes_px, pos_enc,
                                       Xgh, Xgl, Xah, Xal);
  gemm_kernel<<<dim3(43, NKC, 2), 256, 0, stream>>>(Xgh, Xgl, Xah, Xal,
                                                    W_ground, W_aerial, Ypart);
  sim_gemm_kernel<<<dim3(NSIMKC, 2), 256, 0, stream>>>(Ypart, part);
  softmax_kernel<<<200, 128, 0, stream>>>(part, out);
}